// Round 1
// baseline (645.321 us; speedup 1.0000x reference)
//
#include <hip/hip_runtime.h>
#include <math.h>

#define NB 32
#define LL 512
#define PP 256
#define HH 8
#define EE 128
#define DD 1024

__device__ __forceinline__ float gelu_f(float v) {
    return 0.5f * v * (1.0f + erff(v * 0.70710678118654752f));
}

// ---------------- K0: pack mask to bits (row-major + col-major) + no-edge flags
__global__ __launch_bounds__(256) void k0_bits(const float* __restrict__ adj,
                                               unsigned* __restrict__ bits,
                                               unsigned* __restrict__ bitsT,
                                               unsigned* __restrict__ flags) {
    __shared__ unsigned lbits[64][8];
    int n  = blockIdx.x >> 3;
    int l0 = (blockIdx.x & 7) * 64;
    int lane = threadIdx.x & 63;
    int wv   = threadIdx.x >> 6;
    for (int r = wv; r < 64; r += 4) {
        int l = l0 + r;
        const float* row = adj + ((size_t)n * LL + l) * PP;
        int cnt = 0;
        for (int c = 0; c < 4; ++c) {
            float v = row[c * 64 + lane];
            unsigned long long b = __ballot(v != 0.0f);
            if (lane == 0) {
                lbits[r][c * 2]     = (unsigned)b;
                lbits[r][c * 2 + 1] = (unsigned)(b >> 32);
                cnt += __popcll(b);
            }
        }
        if (lane == 0) {
            flags[n * LL + l] = (cnt == 0) ? 1u : 0u;
            for (int w = 0; w < 8; ++w)
                bits[((size_t)n * LL + l) * 8 + w] = lbits[r][w];
        }
    }
    __syncthreads();
    int p = threadIdx.x;  // 0..255
    unsigned w0 = 0, w1 = 0;
    int wp = p >> 5, bp = p & 31;
    for (int j = 0; j < 32; ++j) {
        w0 |= ((lbits[j][wp] >> bp) & 1u) << j;
        w1 |= ((lbits[j + 32][wp] >> bp) & 1u) << j;
    }
    bitsT[((size_t)n * PP + p) * 16 + (l0 >> 5)]     = w0;
    bitsT[((size_t)n * PP + p) * 16 + (l0 >> 5) + 1] = w1;
}

// ---------------- K1: xh = x@W1 + b1 (per head), s = softmax_h(gelu(xh)@W2), eu = exp(a_node - max_h)
__global__ __launch_bounds__(256) void k1_xh(const float* __restrict__ x,
                                             const float* __restrict__ W1,
                                             const float* __restrict__ b1,
                                             const float* __restrict__ W2,
                                             const float* __restrict__ W4,
                                             float* __restrict__ xh,
                                             float* __restrict__ s_out,
                                             float* __restrict__ eu) {
    __shared__ float W1s[64][128];
    __shared__ float xs[4][1024];
    int blk = blockIdx.x;              // 4096 blocks, 4 rows each
    int n  = blk >> 7;
    int l0 = (blk & 127) * 4;
    int tid  = threadIdx.x;
    int wv   = tid >> 6;               // wave -> row
    int lane = tid & 63;
    int f0   = lane * 2;

    {   // stage 4 contiguous x rows (4096 floats)
        const float4* src = (const float4*)(x + ((size_t)n * LL + l0) * DD);
        float4* dst = (float4*)&xs[0][0];
        #pragma unroll
        for (int k = 0; k < 4; ++k) dst[tid + k * 256] = src[tid + k * 256];
    }
    float acc[8][2];
    #pragma unroll
    for (int h = 0; h < 8; ++h) { acc[h][0] = 0.f; acc[h][1] = 0.f; }

    for (int half = 0; half < 2; ++half) {
        __syncthreads();
        {   // stage W1 half (e in [half*64, half*64+64))
            const float4* src = (const float4*)(W1 + half * 64 * 128);
            float4* dst = (float4*)&W1s[0][0];
            #pragma unroll
            for (int k = 0; k < 8; ++k) dst[tid + k * 256] = src[tid + k * 256];
        }
        __syncthreads();
        int ebase = half * 64;
        for (int e4 = 0; e4 < 64; e4 += 4) {
            float2 w1r[4];
            #pragma unroll
            for (int k = 0; k < 4; ++k)
                w1r[k] = *(const float2*)&W1s[e4 + k][f0];
            #pragma unroll
            for (int h = 0; h < 8; ++h) {
                float4 xv = *(const float4*)&xs[wv][h * 128 + ebase + e4];
                acc[h][0] += xv.x * w1r[0].x + xv.y * w1r[1].x + xv.z * w1r[2].x + xv.w * w1r[3].x;
                acc[h][1] += xv.x * w1r[0].y + xv.y * w1r[1].y + xv.z * w1r[2].y + xv.w * w1r[3].y;
            }
        }
    }

    float b1v0 = b1[f0], b1v1 = b1[f0 + 1];
    float w2v0 = W2[f0], w2v1 = W2[f0 + 1];
    float w4v0 = W4[128 + f0], w4v1 = W4[128 + f0 + 1];
    float xvp[8], anp[8];
    int l = l0 + wv;
    #pragma unroll
    for (int h = 0; h < 8; ++h) {
        float v0 = acc[h][0] + b1v0;
        float v1 = acc[h][1] + b1v1;
        float* dst = xh + (((size_t)n * HH + h) * LL + l) * EE;
        *(float2*)&dst[f0] = make_float2(v0, v1);
        float g0 = gelu_f(v0), g1 = gelu_f(v1);
        xvp[h] = g0 * w2v0 + g1 * w2v1;
        anp[h] = g0 * w4v0 + g1 * w4v1;
    }
    for (int off = 32; off > 0; off >>= 1) {
        #pragma unroll
        for (int h = 0; h < 8; ++h) {
            xvp[h] += __shfl_down(xvp[h], off);
            anp[h] += __shfl_down(anp[h], off);
        }
    }
    if (lane == 0) {
        float mx = xvp[0];
        for (int h = 1; h < 8; ++h) mx = fmaxf(mx, xvp[h]);
        float ex[8], ssum = 0.f;
        for (int h = 0; h < 8; ++h) { ex[h] = expf(xvp[h] - mx); ssum += ex[h]; }
        float inv = 1.0f / ssum;
        for (int h = 0; h < 8; ++h) s_out[((size_t)n * HH + h) * LL + l] = ex[h] * inv;
        float mxa = anp[0];
        for (int h = 1; h < 8; ++h) mxa = fmaxf(mxa, anp[h]);
        for (int h = 0; h < 8; ++h) eu[((size_t)n * LL + l) * HH + h] = expf(anp[h] - mxa);
    }
}

// ---------------- K2: he_g[p,e] = gelu( sum_l att_edge[l,p]*xh[l,e] ), att = bit? s[l] : 0.125
__global__ __launch_bounds__(512) void k2_edge(const float* __restrict__ xh,
                                               const float* __restrict__ s_in,
                                               const unsigned* __restrict__ bits,
                                               float* __restrict__ heg) {
    __shared__ float xh_t[64][128];
    __shared__ float s_t[64];
    __shared__ unsigned bt[64][8];
    int bh = blockIdx.x >> 1;        // n*8+h
    int ph = blockIdx.x & 1;         // p half: 128 p's
    int n  = bh >> 3;
    int tid = threadIdx.x;
    int e0 = (tid & 31) * 4;
    int pg = tid >> 5;               // 0..15, 8 p's each
    float4 acc[8];
    #pragma unroll
    for (int i = 0; i < 8; ++i) acc[i] = make_float4(0, 0, 0, 0);
    const float* xh_b = xh + (size_t)bh * LL * EE;
    const float* s_b  = s_in + (size_t)bh * LL;
    const unsigned* bits_b = bits + (size_t)n * LL * 8;
    int wsel = ph * 4 + (pg >> 2);
    int bsh  = (pg & 3) * 8;
    for (int l0 = 0; l0 < LL; l0 += 64) {
        __syncthreads();
        {
            const float4* src = (const float4*)(xh_b + l0 * EE);
            float4* dst = (float4*)&xh_t[0][0];
            #pragma unroll
            for (int k = 0; k < 4; ++k) dst[tid + k * 512] = src[tid + k * 512];
            if (tid < 64) s_t[tid] = s_b[l0 + tid];
            ((unsigned*)bt)[tid] = bits_b[l0 * 8 + tid];
        }
        __syncthreads();
        for (int lr = 0; lr < 64; ++lr) {
            float sl = s_t[lr];
            unsigned bw = (bt[lr][wsel] >> bsh) & 0xFFu;
            float4 xv = *(const float4*)&xh_t[lr][e0];
            #pragma unroll
            for (int i = 0; i < 8; ++i) {
                float a = ((bw >> i) & 1u) ? sl : 0.125f;
                acc[i].x += a * xv.x;
                acc[i].y += a * xv.y;
                acc[i].z += a * xv.z;
                acc[i].w += a * xv.w;
            }
        }
    }
    float* out_b = heg + (size_t)bh * PP * EE;
    #pragma unroll
    for (int i = 0; i < 8; ++i) {
        int p = ph * 128 + pg * 8 + i;
        float4 g;
        g.x = gelu_f(acc[i].x); g.y = gelu_f(acc[i].y);
        g.z = gelu_f(acc[i].z); g.w = gelu_f(acc[i].w);
        *(float4*)&out_b[p * EE + e0] = g;
    }
}

// ---------------- K3: he = he_g@W3 + b3 ; ev = exp(gelu(he)@W4[:E])
__global__ __launch_bounds__(256) void k3_linear3(const float* __restrict__ heg,
                                                  const float* __restrict__ W3,
                                                  const float* __restrict__ b3,
                                                  const float* __restrict__ W4,
                                                  float* __restrict__ he,
                                                  float* __restrict__ ev) {
    __shared__ float W3s[64][128];
    __shared__ float rs[8][128];
    __shared__ float red[4][4];
    int blk = blockIdx.x;            // 8192 blocks, 8 rows each
    size_t r0 = (size_t)blk * 8;
    int tid = threadIdx.x;
    int f = tid & 127, rg = tid >> 7;
    {
        const float4* src = (const float4*)(heg + r0 * 128);
        float4* dst = (float4*)&rs[0][0];
        dst[tid] = src[tid];
    }
    float acc[4] = {0, 0, 0, 0};
    for (int half = 0; half < 2; ++half) {
        __syncthreads();
        {
            const float4* src = (const float4*)(W3 + half * 64 * 128);
            float4* dst = (float4*)&W3s[0][0];
            #pragma unroll
            for (int k = 0; k < 8; ++k) dst[tid + k * 256] = src[tid + k * 256];
        }
        __syncthreads();
        for (int e4 = 0; e4 < 64; e4 += 4) {
            float w3r[4];
            #pragma unroll
            for (int k = 0; k < 4; ++k) w3r[k] = W3s[e4 + k][f];
            #pragma unroll
            for (int j = 0; j < 4; ++j) {
                float4 rv = *(const float4*)&rs[rg * 4 + j][half * 64 + e4];
                acc[j] += rv.x * w3r[0] + rv.y * w3r[1] + rv.z * w3r[2] + rv.w * w3r[3];
            }
        }
    }
    float b3v = b3[f], w4v = W4[f];
    float aep[4];
    #pragma unroll
    for (int j = 0; j < 4; ++j) {
        float v = acc[j] + b3v;
        he[(r0 + rg * 4 + j) * 128 + f] = v;
        aep[j] = gelu_f(v) * w4v;
    }
    int lane = tid & 63, wv = tid >> 6;
    for (int off = 32; off > 0; off >>= 1)
        #pragma unroll
        for (int j = 0; j < 4; ++j) aep[j] += __shfl_down(aep[j], off);
    if (lane == 0)
        for (int j = 0; j < 4; ++j) red[wv][j] = aep[j];
    __syncthreads();
    if (tid < 8) {
        int g = tid >> 2, j = tid & 3;
        float ae = red[g * 2][j] + red[g * 2 + 1][j];
        size_t R = r0 + g * 4 + j;
        int n = (int)(R >> 11);
        int h = (int)((R >> 8) & 7);
        int p = (int)(R & 255);
        ev[((size_t)n * PP + p) * HH + h] = expf(ae);
    }
}

// ---------------- K5: x_nodes = att_node @ he ; out = gelu, transpose, no-edge passthrough
__global__ __launch_bounds__(512) void k5_node(const float* __restrict__ he,
                                               const float* __restrict__ eu,
                                               const float* __restrict__ ev,
                                               const unsigned* __restrict__ bitsT,
                                               const unsigned* __restrict__ flags,
                                               const float* __restrict__ x,
                                               float* __restrict__ out) {
    __shared__ float he_t[64][128];
    __shared__ float eu_t[8][128];
    __shared__ float ev_t[8][256];
    __shared__ float att_t[128][64];
    __shared__ unsigned bT_t[64][4];
    int blk = blockIdx.x;
    int lt = blk & 3;
    int bh = blk >> 2;            // n*8+h
    int n  = bh >> 3;
    int h  = bh & 7;
    int l0 = lt * 128;
    int tid = threadIdx.x;
    int e0 = (tid & 31) * 4;
    int lg = tid >> 5;            // 0..15, 8 l's each
    {   // stage eu (-> [h][l]) and ev (-> [h][p])
        for (int k = tid; k < 1024; k += 512) {
            int li = k >> 3, hh = k & 7;
            eu_t[hh][li] = eu[((size_t)n * LL + l0 + li) * HH + hh];
        }
        for (int k = tid; k < 2048; k += 512) {
            int pi = k >> 3, hh = k & 7;
            ev_t[hh][pi] = ev[((size_t)n * PP + pi) * HH + hh];
        }
    }
    float4 acc[8];
    #pragma unroll
    for (int j = 0; j < 8; ++j) acc[j] = make_float4(0, 0, 0, 0);
    const float* he_b = he + (size_t)bh * PP * EE;
    for (int p0 = 0; p0 < PP; p0 += 64) {
        __syncthreads();
        {
            const float4* src = (const float4*)(he_b + p0 * EE);
            float4* dst = (float4*)&he_t[0][0];
            #pragma unroll
            for (int k = 0; k < 4; ++k) dst[tid + k * 512] = src[tid + k * 512];
        }
        if (tid < 256) {
            int pr = tid >> 2, w = tid & 3;
            bT_t[pr][w] = bitsT[((size_t)n * PP + p0 + pr) * 16 + (l0 >> 5) + w];
        }
        __syncthreads();
        {   // build att tile: each thread a 4l x 4p block
            int lb = tid >> 4;        // 0..31
            int pb = tid & 15;        // 0..15
            int l0b = lb * 4, pp0 = pb * 4;
            float den[4][4], num[4][4];
            #pragma unroll
            for (int a = 0; a < 4; ++a)
                #pragma unroll
                for (int b = 0; b < 4; ++b) den[a][b] = 0.f;
            #pragma unroll
            for (int hh = 0; hh < 8; ++hh) {
                float4 euv = *(const float4*)&eu_t[hh][l0b];
                float4 evv = *(const float4*)&ev_t[hh][p0 + pp0];
                float eua[4] = {euv.x, euv.y, euv.z, euv.w};
                float eva[4] = {evv.x, evv.y, evv.z, evv.w};
                #pragma unroll
                for (int a = 0; a < 4; ++a)
                    #pragma unroll
                    for (int b = 0; b < 4; ++b)
                        den[a][b] += eua[a] * eva[b];
                if (hh == h)
                    #pragma unroll
                    for (int a = 0; a < 4; ++a)
                        #pragma unroll
                        for (int b = 0; b < 4; ++b)
                            num[a][b] = eua[a] * eva[b];
            }
            int wrd = lb >> 3;
            #pragma unroll
            for (int b = 0; b < 4; ++b) {
                unsigned w32 = bT_t[pp0 + b][wrd];
                #pragma unroll
                for (int a = 0; a < 4; ++a) {
                    unsigned bit = (w32 >> ((l0b + a) & 31)) & 1u;
                    att_t[l0b + a][pp0 + b] = bit ? (num[a][b] / den[a][b]) : 0.125f;
                }
            }
        }
        __syncthreads();
        for (int pr = 0; pr < 64; ++pr) {
            float4 hv = *(const float4*)&he_t[pr][e0];
            #pragma unroll
            for (int j = 0; j < 8; ++j) {
                float a = att_t[lg * 8 + j][pr];
                acc[j].x += a * hv.x;
                acc[j].y += a * hv.y;
                acc[j].z += a * hv.z;
                acc[j].w += a * hv.w;
            }
        }
    }
    #pragma unroll
    for (int j = 0; j < 8; ++j) {
        int l = l0 + lg * 8 + j;
        unsigned fl = flags[n * LL + l];
        float* dst = out + ((size_t)n * LL + l) * DD + h * EE + e0;
        if (fl) {
            const float* xs = x + ((size_t)n * LL + l) * DD + h * EE + e0;
            *(float4*)dst = *(const float4*)xs;
        } else {
            float4 g;
            g.x = gelu_f(acc[j].x); g.y = gelu_f(acc[j].y);
            g.z = gelu_f(acc[j].z); g.w = gelu_f(acc[j].w);
            *(float4*)dst = g;
        }
    }
}

extern "C" void kernel_launch(void* const* d_in, const int* in_sizes, int n_in,
                              void* d_out, int out_size, void* d_ws, size_t ws_size,
                              hipStream_t stream) {
    (void)in_sizes; (void)n_in; (void)out_size; (void)ws_size;
    const float* x   = (const float*)d_in[0];
    const float* adj = (const float*)d_in[1];
    const float* W1  = (const float*)d_in[2];
    const float* b1  = (const float*)d_in[3];
    const float* W2  = (const float*)d_in[4];
    const float* W3  = (const float*)d_in[6];
    const float* b3  = (const float*)d_in[7];
    const float* W4  = (const float*)d_in[8];
    float* out = (float*)d_out;

    char* ws = (char*)d_ws;
    size_t off = 0;
    auto alloc = [&](size_t bytes) -> void* {
        void* p = ws + off;
        off += (bytes + 255) & ~(size_t)255;
        return p;
    };
    float* xh   = (float*)alloc((size_t)NB * HH * LL * EE * 4);   // 67 MB
    float* s    = (float*)alloc((size_t)NB * HH * LL * 4);
    float* eu   = (float*)alloc((size_t)NB * LL * HH * 4);
    float* ev   = (float*)alloc((size_t)NB * PP * HH * 4);
    float* heg  = (float*)alloc((size_t)NB * HH * PP * EE * 4);   // 33.5 MB
    float* he   = (float*)alloc((size_t)NB * HH * PP * EE * 4);   // 33.5 MB
    unsigned* bits  = (unsigned*)alloc((size_t)NB * LL * 8 * 4);
    unsigned* bitsT = (unsigned*)alloc((size_t)NB * PP * 16 * 4);
    unsigned* flags = (unsigned*)alloc((size_t)NB * LL * 4);

    hipLaunchKernelGGL(k0_bits, dim3(NB * 8), dim3(256), 0, stream, adj, bits, bitsT, flags);
    hipLaunchKernelGGL(k1_xh, dim3(NB * 128), dim3(256), 0, stream, x, W1, b1, W2, W4, xh, s, eu);
    hipLaunchKernelGGL(k2_edge, dim3(NB * HH * 2), dim3(512), 0, stream, xh, s, bits, heg);
    hipLaunchKernelGGL(k3_linear3, dim3(NB * HH * PP / 8), dim3(256), 0, stream, heg, W3, b3, W4, he, ev);
    hipLaunchKernelGGL(k5_node, dim3(NB * HH * 4), dim3(512), 0, stream, he, eu, ev, bitsT, flags, x, out);
}

// Round 2
// 618.740 us; speedup vs baseline: 1.0430x; 1.0430x over previous
//
#include <hip/hip_runtime.h>
#include <math.h>

#define NB 32
#define LL 512
#define PP 256
#define HH 8
#define EE 128
#define DD 1024

__device__ __forceinline__ float gelu_f(float v) {
    return 0.5f * v * (1.0f + erff(v * 0.70710678118654752f));
}

__device__ __forceinline__ float rcp_f(float v) {
    float r;
    asm("v_rcp_f32 %0, %1" : "=v"(r) : "v"(v));
    return r;
}

// ---------------- K0: pack mask to bits (row-major + col-major) + no-edge flags
__global__ __launch_bounds__(256) void k0_bits(const float* __restrict__ adj,
                                               unsigned* __restrict__ bits,
                                               unsigned* __restrict__ bitsT,
                                               unsigned* __restrict__ flags) {
    __shared__ unsigned lbits[64][8];
    int n  = blockIdx.x >> 3;
    int l0 = (blockIdx.x & 7) * 64;
    int lane = threadIdx.x & 63;
    int wv   = threadIdx.x >> 6;
    for (int r = wv; r < 64; r += 4) {
        int l = l0 + r;
        const float* row = adj + ((size_t)n * LL + l) * PP;
        int cnt = 0;
        for (int c = 0; c < 4; ++c) {
            float v = row[c * 64 + lane];
            unsigned long long b = __ballot(v != 0.0f);
            if (lane == 0) {
                lbits[r][c * 2]     = (unsigned)b;
                lbits[r][c * 2 + 1] = (unsigned)(b >> 32);
                cnt += __popcll(b);
            }
        }
        if (lane == 0) {
            flags[n * LL + l] = (cnt == 0) ? 1u : 0u;
            for (int w = 0; w < 8; ++w)
                bits[((size_t)n * LL + l) * 8 + w] = lbits[r][w];
        }
    }
    __syncthreads();
    int p = threadIdx.x;  // 0..255
    unsigned w0 = 0, w1 = 0;
    int wp = p >> 5, bp = p & 31;
    for (int j = 0; j < 32; ++j) {
        w0 |= ((lbits[j][wp] >> bp) & 1u) << j;
        w1 |= ((lbits[j + 32][wp] >> bp) & 1u) << j;
    }
    bitsT[((size_t)n * PP + p) * 16 + (l0 >> 5)]     = w0;
    bitsT[((size_t)n * PP + p) * 16 + (l0 >> 5) + 1] = w1;
}

// ---------------- K1: xh = x@W1 + b1 (per head), s = softmax_h(gelu(xh)@W2), eu = exp(a_node - max_h)
__global__ __launch_bounds__(256) void k1_xh(const float* __restrict__ x,
                                             const float* __restrict__ W1,
                                             const float* __restrict__ b1,
                                             const float* __restrict__ W2,
                                             const float* __restrict__ W4,
                                             float* __restrict__ xh,
                                             float* __restrict__ s_out,
                                             float* __restrict__ eu) {
    __shared__ float W1s[64][128];
    __shared__ float xs[4][1024];
    int blk = blockIdx.x;              // 4096 blocks, 4 rows each
    int n  = blk >> 7;
    int l0 = (blk & 127) * 4;
    int tid  = threadIdx.x;
    int wv   = tid >> 6;               // wave -> row
    int lane = tid & 63;
    int f0   = lane * 2;

    {   // stage 4 contiguous x rows (4096 floats)
        const float4* src = (const float4*)(x + ((size_t)n * LL + l0) * DD);
        float4* dst = (float4*)&xs[0][0];
        #pragma unroll
        for (int k = 0; k < 4; ++k) dst[tid + k * 256] = src[tid + k * 256];
    }
    float acc[8][2];
    #pragma unroll
    for (int h = 0; h < 8; ++h) { acc[h][0] = 0.f; acc[h][1] = 0.f; }

    for (int half = 0; half < 2; ++half) {
        __syncthreads();
        {   // stage W1 half (e in [half*64, half*64+64))
            const float4* src = (const float4*)(W1 + half * 64 * 128);
            float4* dst = (float4*)&W1s[0][0];
            #pragma unroll
            for (int k = 0; k < 8; ++k) dst[tid + k * 256] = src[tid + k * 256];
        }
        __syncthreads();
        int ebase = half * 64;
        for (int e4 = 0; e4 < 64; e4 += 4) {
            float2 w1r[4];
            #pragma unroll
            for (int k = 0; k < 4; ++k)
                w1r[k] = *(const float2*)&W1s[e4 + k][f0];
            #pragma unroll
            for (int h = 0; h < 8; ++h) {
                float4 xv = *(const float4*)&xs[wv][h * 128 + ebase + e4];
                acc[h][0] += xv.x * w1r[0].x + xv.y * w1r[1].x + xv.z * w1r[2].x + xv.w * w1r[3].x;
                acc[h][1] += xv.x * w1r[0].y + xv.y * w1r[1].y + xv.z * w1r[2].y + xv.w * w1r[3].y;
            }
        }
    }

    float b1v0 = b1[f0], b1v1 = b1[f0 + 1];
    float w2v0 = W2[f0], w2v1 = W2[f0 + 1];
    float w4v0 = W4[128 + f0], w4v1 = W4[128 + f0 + 1];
    float xvp[8], anp[8];
    int l = l0 + wv;
    #pragma unroll
    for (int h = 0; h < 8; ++h) {
        float v0 = acc[h][0] + b1v0;
        float v1 = acc[h][1] + b1v1;
        float* dst = xh + (((size_t)n * HH + h) * LL + l) * EE;
        *(float2*)&dst[f0] = make_float2(v0, v1);
        float g0 = gelu_f(v0), g1 = gelu_f(v1);
        xvp[h] = g0 * w2v0 + g1 * w2v1;
        anp[h] = g0 * w4v0 + g1 * w4v1;
    }
    for (int off = 32; off > 0; off >>= 1) {
        #pragma unroll
        for (int h = 0; h < 8; ++h) {
            xvp[h] += __shfl_down(xvp[h], off);
            anp[h] += __shfl_down(anp[h], off);
        }
    }
    if (lane == 0) {
        float mx = xvp[0];
        for (int h = 1; h < 8; ++h) mx = fmaxf(mx, xvp[h]);
        float ex[8], ssum = 0.f;
        for (int h = 0; h < 8; ++h) { ex[h] = expf(xvp[h] - mx); ssum += ex[h]; }
        float inv = 1.0f / ssum;
        for (int h = 0; h < 8; ++h) s_out[((size_t)n * HH + h) * LL + l] = ex[h] * inv;
        float mxa = anp[0];
        for (int h = 1; h < 8; ++h) mxa = fmaxf(mxa, anp[h]);
        for (int h = 0; h < 8; ++h) eu[((size_t)n * LL + l) * HH + h] = expf(anp[h] - mxa);
    }
}

// ---------------- K2 (sparse): heg[p,e] = gelu( 0.125*colsum_xh[e] + sum_{l in bits(p)} (s[l]-0.125)*xh[l,e] )
__global__ __launch_bounds__(512) void k2_edge_sparse(const float* __restrict__ xh,
                                                      const float* __restrict__ s_in,
                                                      const unsigned* __restrict__ bitsT,
                                                      float* __restrict__ heg) {
    __shared__ float xh_t[128][128];     // 64 KB
    __shared__ float s_t[128];
    __shared__ unsigned bT[128][4];      // 2 KB
    __shared__ float red[8][128];        // 4 KB
    int blk = blockIdx.x;                // (bh<<1) | ph
    int ph  = blk & 1;
    int bh  = blk >> 1;                  // n*8+h
    int n   = bh >> 3;
    int tid = threadIdx.x;
    int lane = tid & 63;
    int wv   = tid >> 6;
    int e0 = lane * 2;

    float2 acc[16];
    #pragma unroll
    for (int g = 0; g < 16; ++g) acc[g] = make_float2(0.f, 0.f);
    float2 csum = make_float2(0.f, 0.f);

    const float* xh_b = xh + (size_t)bh * (LL * EE);
    const float* s_b  = s_in + (size_t)bh * LL;
    const unsigned* bT_b = bitsT + (size_t)n * (PP * 16);

    for (int lt = 0; lt < 4; ++lt) {
        __syncthreads();
        {   // stage xh tile: 128 rows x 128 e = 4096 float4
            const float4* src = (const float4*)(xh_b + lt * 128 * EE);
            float4* dst = (float4*)&xh_t[0][0];
            #pragma unroll
            for (int k = 0; k < 8; ++k) dst[tid + k * 512] = src[tid + k * 512];
        }
        if (tid < 128) s_t[tid] = s_b[lt * 128 + tid] - 0.125f;
        {   // stage bits: 128 p x 4 words
            int p = ph * 128 + (tid >> 2);
            bT[tid >> 2][tid & 3] = bT_b[p * 16 + lt * 4 + (tid & 3)];
        }
        __syncthreads();
        // colsum partial: this wave's 16 rows of the tile
        #pragma unroll
        for (int r = 0; r < 16; ++r) {
            float2 v = *(const float2*)&xh_t[wv * 16 + r][e0];
            csum.x += v.x; csum.y += v.y;
        }
        // sparse accumulate: wave owns p's [wv*16, wv*16+16) of this half
        #pragma unroll
        for (int g = 0; g < 16; ++g) {
            int prow = wv * 16 + g;
            #pragma unroll
            for (int w = 0; w < 4; ++w) {
                unsigned bw = bT[prow][w];
                int lb = w * 32;
                while (bw) {
                    int j = __ffs(bw) - 1;
                    bw &= bw - 1;
                    float2 v = *(const float2*)&xh_t[lb + j][e0];
                    float c = s_t[lb + j];
                    acc[g].x += c * v.x;
                    acc[g].y += c * v.y;
                }
            }
        }
    }
    __syncthreads();
    red[wv][e0] = csum.x; red[wv][e0 + 1] = csum.y;
    __syncthreads();
    float cs0 = 0.f, cs1 = 0.f;
    #pragma unroll
    for (int w2 = 0; w2 < 8; ++w2) { cs0 += red[w2][e0]; cs1 += red[w2][e0 + 1]; }
    cs0 *= 0.125f; cs1 *= 0.125f;

    float* out_b = heg + (size_t)bh * (PP * EE);
    #pragma unroll
    for (int g = 0; g < 16; ++g) {
        int p = ph * 128 + wv * 16 + g;
        float v0 = cs0 + acc[g].x;
        float v1 = cs1 + acc[g].y;
        *(float2*)&out_b[p * EE + e0] = make_float2(gelu_f(v0), gelu_f(v1));
    }
}

// ---------------- K3: he = heg@W3 + b3 ; ev = exp(gelu(he)@W4[:E])
__global__ __launch_bounds__(256) void k3_linear3(const float* __restrict__ heg,
                                                  const float* __restrict__ W3,
                                                  const float* __restrict__ b3,
                                                  const float* __restrict__ W4,
                                                  float* __restrict__ he,
                                                  float* __restrict__ ev) {
    __shared__ float W3s[64][128];
    __shared__ float rs[8][128];
    __shared__ float red[4][4];
    int blk = blockIdx.x;            // 8192 blocks, 8 rows each
    size_t r0 = (size_t)blk * 8;
    int tid = threadIdx.x;
    int f = tid & 127, rg = tid >> 7;
    {
        const float4* src = (const float4*)(heg + r0 * 128);
        float4* dst = (float4*)&rs[0][0];
        dst[tid] = src[tid];
    }
    float acc[4] = {0, 0, 0, 0};
    for (int half = 0; half < 2; ++half) {
        __syncthreads();
        {
            const float4* src = (const float4*)(W3 + half * 64 * 128);
            float4* dst = (float4*)&W3s[0][0];
            #pragma unroll
            for (int k = 0; k < 8; ++k) dst[tid + k * 256] = src[tid + k * 256];
        }
        __syncthreads();
        for (int e4 = 0; e4 < 64; e4 += 4) {
            float w3r[4];
            #pragma unroll
            for (int k = 0; k < 4; ++k) w3r[k] = W3s[e4 + k][f];
            #pragma unroll
            for (int j = 0; j < 4; ++j) {
                float4 rv = *(const float4*)&rs[rg * 4 + j][half * 64 + e4];
                acc[j] += rv.x * w3r[0] + rv.y * w3r[1] + rv.z * w3r[2] + rv.w * w3r[3];
            }
        }
    }
    float b3v = b3[f], w4v = W4[f];
    float aep[4];
    #pragma unroll
    for (int j = 0; j < 4; ++j) {
        float v = acc[j] + b3v;
        he[(r0 + rg * 4 + j) * 128 + f] = v;
        aep[j] = gelu_f(v) * w4v;
    }
    int lane = tid & 63, wv = tid >> 6;
    for (int off = 32; off > 0; off >>= 1)
        #pragma unroll
        for (int j = 0; j < 4; ++j) aep[j] += __shfl_down(aep[j], off);
    if (lane == 0)
        for (int j = 0; j < 4; ++j) red[wv][j] = aep[j];
    __syncthreads();
    if (tid < 8) {
        int g = tid >> 2, j = tid & 3;
        float ae = red[g * 2][j] + red[g * 2 + 1][j];
        size_t R = r0 + g * 4 + j;
        int n = (int)(R >> 11);
        int h = (int)((R >> 8) & 7);
        int p = (int)(R & 255);
        ev[((size_t)n * PP + p) * HH + h] = expf(ae);
    }
}

// ---------------- K5 (sparse): x_nodes[l,e] = 0.125*colsum_he[e] + sum_{p in bits(l)} (eu_h ev_h/den - 0.125)*he[p,e]
__global__ __launch_bounds__(512) void k5_node_sparse(const float* __restrict__ he,
                                                      const float* __restrict__ eu,
                                                      const float* __restrict__ ev,
                                                      const unsigned* __restrict__ bits,
                                                      const unsigned* __restrict__ flags,
                                                      const float* __restrict__ x,
                                                      float* __restrict__ out) {
    __shared__ float he_t[256][128];     // 128 KB
    __shared__ float ev_t[256][8];       // 8 KB
    __shared__ float eu_t[256][8];       // 8 KB
    __shared__ unsigned bt[256][8];      // 8 KB
    __shared__ float red[8][128];        // 4 KB  (total 156 KB)
    int blk = blockIdx.x;
    int lh  = blk & 1;                   // l half
    int bh  = blk >> 1;                  // n*8+h
    int n   = bh >> 3, h = bh & 7;
    int tid = threadIdx.x, lane = tid & 63, wv = tid >> 6;
    int e0 = lane * 2;

    {   // stage he panel (256x128), ev, eu, bits
        const float4* src = (const float4*)(he + (size_t)bh * PP * EE);
        float4* dst = (float4*)&he_t[0][0];
        #pragma unroll
        for (int k = 0; k < 16; ++k) dst[tid + k * 512] = src[tid + k * 512];
        ((float4*)ev_t)[tid] = ((const float4*)(ev + (size_t)n * PP * HH))[tid];
        ((float4*)eu_t)[tid] = ((const float4*)(eu + ((size_t)n * LL + lh * 256) * HH))[tid];
        ((uint4*)bt)[tid]    = ((const uint4*)(bits + ((size_t)n * LL + lh * 256) * 8))[tid];
    }
    __syncthreads();
    // colsum over all 256 p
    float2 csum = make_float2(0.f, 0.f);
    #pragma unroll
    for (int r = 0; r < 32; ++r) {
        float2 v = *(const float2*)&he_t[wv * 32 + r][e0];
        csum.x += v.x; csum.y += v.y;
    }
    red[wv][e0] = csum.x; red[wv][e0 + 1] = csum.y;
    __syncthreads();
    float cs0 = 0.f, cs1 = 0.f;
    #pragma unroll
    for (int w2 = 0; w2 < 8; ++w2) { cs0 += red[w2][e0]; cs1 += red[w2][e0 + 1]; }
    cs0 *= 0.125f; cs1 *= 0.125f;

    for (int i = 0; i < 32; ++i) {
        int lrow = wv * 32 + i;
        float4 eua = *(const float4*)&eu_t[lrow][0];
        float4 eub = *(const float4*)&eu_t[lrow][4];
        float euh = eu_t[lrow][h];
        float ax = 0.f, ay = 0.f;
        #pragma unroll
        for (int w = 0; w < 8; ++w) {
            unsigned bw = bt[lrow][w];
            int pb = w * 32;
            while (bw) {
                int j = __ffs(bw) - 1;
                bw &= bw - 1;
                int p = pb + j;
                float2 hv = *(const float2*)&he_t[p][e0];
                float4 e0v = *(const float4*)&ev_t[p][0];
                float4 e1v = *(const float4*)&ev_t[p][4];
                float evh = ev_t[p][h];
                float den = eua.x * e0v.x + eua.y * e0v.y + eua.z * e0v.z + eua.w * e0v.w
                          + eub.x * e1v.x + eub.y * e1v.y + eub.z * e1v.z + eub.w * e1v.w;
                float c = rcp_f(den) * euh * evh - 0.125f;
                ax += c * hv.x;
                ay += c * hv.y;
            }
        }
        int l = lh * 256 + lrow;
        float* dst = out + ((size_t)n * LL + l) * DD + h * EE + e0;
        if (flags[n * LL + l]) {
            const float* xs = x + ((size_t)n * LL + l) * DD + h * EE + e0;
            *(float2*)dst = *(const float2*)xs;
        } else {
            *(float2*)dst = make_float2(gelu_f(cs0 + ax), gelu_f(cs1 + ay));
        }
    }
}

extern "C" void kernel_launch(void* const* d_in, const int* in_sizes, int n_in,
                              void* d_out, int out_size, void* d_ws, size_t ws_size,
                              hipStream_t stream) {
    (void)in_sizes; (void)n_in; (void)out_size; (void)ws_size;
    const float* x   = (const float*)d_in[0];
    const float* adj = (const float*)d_in[1];
    const float* W1  = (const float*)d_in[2];
    const float* b1  = (const float*)d_in[3];
    const float* W2  = (const float*)d_in[4];
    const float* W3  = (const float*)d_in[6];
    const float* b3  = (const float*)d_in[7];
    const float* W4  = (const float*)d_in[8];
    float* out = (float*)d_out;

    char* ws = (char*)d_ws;
    size_t off = 0;
    auto alloc = [&](size_t bytes) -> void* {
        void* p = ws + off;
        off += (bytes + 255) & ~(size_t)255;
        return p;
    };
    float* xh   = (float*)alloc((size_t)NB * HH * LL * EE * 4);   // 67 MB
    float* s    = (float*)alloc((size_t)NB * HH * LL * 4);
    float* eu   = (float*)alloc((size_t)NB * LL * HH * 4);
    float* ev   = (float*)alloc((size_t)NB * PP * HH * 4);
    float* heg  = (float*)alloc((size_t)NB * HH * PP * EE * 4);   // 33.5 MB
    float* he   = (float*)alloc((size_t)NB * HH * PP * EE * 4);   // 33.5 MB
    unsigned* bits  = (unsigned*)alloc((size_t)NB * LL * 8 * 4);
    unsigned* bitsT = (unsigned*)alloc((size_t)NB * PP * 16 * 4);
    unsigned* flags = (unsigned*)alloc((size_t)NB * LL * 4);

    hipLaunchKernelGGL(k0_bits, dim3(NB * 8), dim3(256), 0, stream, adj, bits, bitsT, flags);
    hipLaunchKernelGGL(k1_xh, dim3(NB * 128), dim3(256), 0, stream, x, W1, b1, W2, W4, xh, s, eu);
    hipLaunchKernelGGL(k2_edge_sparse, dim3(NB * HH * 2), dim3(512), 0, stream, xh, s, bitsT, heg);
    hipLaunchKernelGGL(k3_linear3, dim3(NB * HH * PP / 8), dim3(256), 0, stream, heg, W3, b3, W4, he, ev);
    hipLaunchKernelGGL(k5_node_sparse, dim3(NB * HH * 2), dim3(512), 0, stream, he, eu, ev, bits, flags, x, out);
}

// Round 3
// 486.163 us; speedup vs baseline: 1.3274x; 1.2727x over previous
//
#include <hip/hip_runtime.h>
#include <math.h>

#define NB 32
#define LL 512
#define PP 256
#define HH 8
#define EE 128
#define DD 1024

typedef __attribute__((ext_vector_type(4))) float f32x4;
typedef __attribute__((ext_vector_type(8))) short short8;

__device__ __forceinline__ float gelu_f(float v) {
    return 0.5f * v * (1.0f + erff(v * 0.70710678118654752f));
}
__device__ __forceinline__ float rcp_f(float v) {
    float r; asm("v_rcp_f32 %0, %1" : "=v"(r) : "v"(v)); return r;
}
__device__ __forceinline__ unsigned short bf16_rne(float v) {
    unsigned u = __float_as_uint(v);
    unsigned r = u + 0x7FFFu + ((u >> 16) & 1u);
    return (unsigned short)(r >> 16);
}
__device__ __forceinline__ f32x4 gelu4(f32x4 v) {
    f32x4 g; g.x = gelu_f(v.x); g.y = gelu_f(v.y); g.z = gelu_f(v.z); g.w = gelu_f(v.w); return g;
}

// ---------------- kpack: W (128x128 fp32) -> bf16 hi/lo in MFMA B-fragment order
// Bp[(oct*128 + col)*8 + j] = W[oct*8 + j][col]
__global__ __launch_bounds__(256) void kpack(const float* __restrict__ W1,
                                             const float* __restrict__ W3,
                                             unsigned short* __restrict__ W1h,
                                             unsigned short* __restrict__ W1l,
                                             unsigned short* __restrict__ W3h,
                                             unsigned short* __restrict__ W3l) {
    const float* W = blockIdx.x ? W3 : W1;
    unsigned short* Ph = blockIdx.x ? W3h : W1h;
    unsigned short* Pl = blockIdx.x ? W3l : W1l;
    for (int i = threadIdx.x; i < 16384; i += 256) {
        int oct = i >> 10, col = (i >> 3) & 127, j = i & 7;
        float v = W[(oct * 8 + j) * 128 + col];
        unsigned short hb = bf16_rne(v);
        float hf = __uint_as_float((unsigned)hb << 16);
        Ph[i] = hb;
        Pl[i] = bf16_rne(v - hf);
    }
}

// ---------------- K0: pack mask to bits (row-major + col-major) + no-edge flags
__global__ __launch_bounds__(256) void k0_bits(const float* __restrict__ adj,
                                               unsigned* __restrict__ bits,
                                               unsigned* __restrict__ bitsT,
                                               unsigned* __restrict__ flags) {
    __shared__ unsigned lbits[64][8];
    int n  = blockIdx.x >> 3;
    int l0 = (blockIdx.x & 7) * 64;
    int lane = threadIdx.x & 63;
    int wv   = threadIdx.x >> 6;
    for (int r = wv; r < 64; r += 4) {
        int l = l0 + r;
        const float* row = adj + ((size_t)n * LL + l) * PP;
        int cnt = 0;
        for (int c = 0; c < 4; ++c) {
            float v = row[c * 64 + lane];
            unsigned long long b = __ballot(v != 0.0f);
            if (lane == 0) {
                lbits[r][c * 2]     = (unsigned)b;
                lbits[r][c * 2 + 1] = (unsigned)(b >> 32);
                cnt += __popcll(b);
            }
        }
        if (lane == 0) {
            flags[n * LL + l] = (cnt == 0) ? 1u : 0u;
            for (int w = 0; w < 8; ++w)
                bits[((size_t)n * LL + l) * 8 + w] = lbits[r][w];
        }
    }
    __syncthreads();
    int p = threadIdx.x;
    unsigned w0 = 0, w1 = 0;
    int wp = p >> 5, bp = p & 31;
    for (int j = 0; j < 32; ++j) {
        w0 |= ((lbits[j][wp] >> bp) & 1u) << j;
        w1 |= ((lbits[j + 32][wp] >> bp) & 1u) << j;
    }
    bitsT[((size_t)n * PP + p) * 16 + (l0 >> 5)]     = w0;
    bitsT[((size_t)n * PP + p) * 16 + (l0 >> 5) + 1] = w1;
}

// ---------------- gemm128: C[M x 128] = A[M x 128] @ W[128 x 128] + bias
// 3-pass bf16 split MFMA (hi*hi + hi*lo + lo*hi), fp32-grade accuracy.
// Block: 256 thr (4 waves), 128 rows/block (wave = 2 m-tiles of 16).
__global__ __launch_bounds__(256) void gemm128(const float* __restrict__ A,
                                               const unsigned short* __restrict__ Bhi,
                                               const unsigned short* __restrict__ Blo,
                                               const float* __restrict__ bias,
                                               float* __restrict__ C) {
    int tid = threadIdx.x, lane = tid & 63, w = tid >> 6;
    size_t rowbase = (size_t)blockIdx.x * 128 + w * 32;
    int rl = lane & 15, g = lane >> 4;
    f32x4 acc[2][8];
    #pragma unroll
    for (int t = 0; t < 2; ++t)
        #pragma unroll
        for (int nt = 0; nt < 8; ++nt) acc[t][nt] = (f32x4){0.f, 0.f, 0.f, 0.f};

    #pragma unroll
    for (int kc = 0; kc < 4; ++kc) {
        short8 ah[2], al[2];
        #pragma unroll
        for (int t = 0; t < 2; ++t) {
            const float* ap = A + (rowbase + t * 16 + rl) * 128 + kc * 32 + g * 8;
            f32x4 a0 = *(const f32x4*)ap;
            f32x4 a1 = *(const f32x4*)(ap + 4);
            float av[8] = {a0.x, a0.y, a0.z, a0.w, a1.x, a1.y, a1.z, a1.w};
            #pragma unroll
            for (int j = 0; j < 8; ++j) {
                unsigned short hb = bf16_rne(av[j]);
                float hf = __uint_as_float((unsigned)hb << 16);
                ah[t][j] = (short)hb;
                al[t][j] = (short)bf16_rne(av[j] - hf);
            }
        }
        #pragma unroll
        for (int nt = 0; nt < 8; ++nt) {
            int oct = kc * 4 + g, col = nt * 16 + rl;
            short8 bh = *(const short8*)(Bhi + ((size_t)(oct * 128 + col)) * 8);
            short8 bl = *(const short8*)(Blo + ((size_t)(oct * 128 + col)) * 8);
            #pragma unroll
            for (int t = 0; t < 2; ++t) {
                acc[t][nt] = __builtin_amdgcn_mfma_f32_16x16x32_bf16(ah[t], bh, acc[t][nt], 0, 0, 0);
                acc[t][nt] = __builtin_amdgcn_mfma_f32_16x16x32_bf16(ah[t], bl, acc[t][nt], 0, 0, 0);
                acc[t][nt] = __builtin_amdgcn_mfma_f32_16x16x32_bf16(al[t], bh, acc[t][nt], 0, 0, 0);
            }
        }
    }
    #pragma unroll
    for (int nt = 0; nt < 8; ++nt) {
        int col = nt * 16 + rl;
        float bv = bias[col];
        #pragma unroll
        for (int t = 0; t < 2; ++t)
            #pragma unroll
            for (int r = 0; r < 4; ++r) {
                size_t row = rowbase + t * 16 + g * 4 + r;
                C[row * 128 + col] = acc[t][nt][r] + bv;
            }
    }
}

// ---------------- k1b: s = softmax_h(gelu(xh)@W2), eu = exp(a_node - max_h)
// xh layout: [(n*512+l)*8 + h][128]; wave per (n,l) row; lane: h=lane>>3, sub=lane&7
__global__ __launch_bounds__(256) void k1b_softmax(const float* __restrict__ xh,
                                                   const float* __restrict__ W2,
                                                   const float* __restrict__ W4,
                                                   float* __restrict__ s_out,
                                                   float* __restrict__ eu) {
    int tid = threadIdx.x, lane = tid & 63, wv = tid >> 6;
    int base = blockIdx.x * 4 + wv;
    int n = base >> 9, l = base & 511;
    int h = lane >> 3, sub = lane & 7;
    const float* xp = xh + (size_t)base * 1024 + h * 128 + sub * 16;
    float xv = 0.f, an = 0.f;
    #pragma unroll
    for (int q = 0; q < 4; ++q) {
        f32x4 v  = *(const f32x4*)(xp + q * 4);
        f32x4 w2 = *(const f32x4*)(W2 + sub * 16 + q * 4);
        f32x4 w4 = *(const f32x4*)(W4 + 128 + sub * 16 + q * 4);
        f32x4 gv = gelu4(v);
        xv += gv.x * w2.x + gv.y * w2.y + gv.z * w2.z + gv.w * w2.w;
        an += gv.x * w4.x + gv.y * w4.y + gv.z * w4.z + gv.w * w4.w;
    }
    xv += __shfl_xor(xv, 1); xv += __shfl_xor(xv, 2); xv += __shfl_xor(xv, 4);
    an += __shfl_xor(an, 1); an += __shfl_xor(an, 2); an += __shfl_xor(an, 4);
    float mx = xv;
    mx = fmaxf(mx, __shfl_xor(mx, 8)); mx = fmaxf(mx, __shfl_xor(mx, 16)); mx = fmaxf(mx, __shfl_xor(mx, 32));
    float ex = expf(xv - mx);
    float sm = ex;
    sm += __shfl_xor(sm, 8); sm += __shfl_xor(sm, 16); sm += __shfl_xor(sm, 32);
    float sv = ex / sm;
    float mxa = an;
    mxa = fmaxf(mxa, __shfl_xor(mxa, 8)); mxa = fmaxf(mxa, __shfl_xor(mxa, 16)); mxa = fmaxf(mxa, __shfl_xor(mxa, 32));
    float euv = expf(an - mxa);
    if (sub == 0) {
        s_out[((size_t)(n * 8 + h)) * 512 + l] = sv;
        eu[(size_t)base * 8 + h] = euv;
    }
}

// ---------------- K2 (sparse, bit-pair): heg[p,e] = gelu(0.125*colsum + sum_{l in bits(p)} (s[l]-0.125)*xh[l,e])
__global__ __launch_bounds__(512) void k2_edge_sparse(const float* __restrict__ xh,
                                                      const float* __restrict__ s_in,
                                                      const unsigned* __restrict__ bitsT,
                                                      float* __restrict__ heg) {
    __shared__ float xh_t[128][128];     // 64 KB
    __shared__ float s_t[128];
    __shared__ unsigned bT[128][4];
    __shared__ float red[8][128];
    int blk = blockIdx.x;
    int ph  = blk & 1;
    int bh  = blk >> 1;
    int n   = bh >> 3, h = bh & 7;
    int tid = threadIdx.x, lane = tid & 63, wv = tid >> 6;
    int lx = lane & 31, hsel = lane >> 5;

    f32x4 acc[16];
    #pragma unroll
    for (int g2 = 0; g2 < 16; ++g2) acc[g2] = (f32x4){0.f, 0.f, 0.f, 0.f};
    f32x4 csum = (f32x4){0.f, 0.f, 0.f, 0.f};

    for (int lt = 0; lt < 4; ++lt) {
        __syncthreads();
        #pragma unroll
        for (int pass = 0; pass < 8; ++pass) {
            int r = pass * 16 + (tid >> 5);
            *(f32x4*)&xh_t[r][(tid & 31) * 4] =
                *(const f32x4*)(xh + (((size_t)(n * 512 + lt * 128 + r)) * 8 + h) * 128 + (tid & 31) * 4);
        }
        if (tid < 128) s_t[tid] = s_in[(size_t)bh * 512 + lt * 128 + tid] - 0.125f;
        { int p = ph * 128 + (tid >> 2);
          bT[tid >> 2][tid & 3] = bitsT[((size_t)(n * 256 + p)) * 16 + lt * 4 + (tid & 3)]; }
        __syncthreads();
        #pragma unroll
        for (int r = 0; r < 16; ++r) csum += *(const f32x4*)&xh_t[wv * 16 + r][lx * 4];
        #pragma unroll
        for (int g2 = 0; g2 < 16; ++g2) {
            int prow = wv * 16 + g2;
            #pragma unroll
            for (int w64 = 0; w64 < 2; ++w64) {
                unsigned long long bw = bT[prow][w64 * 2] | ((unsigned long long)bT[prow][w64 * 2 + 1] << 32);
                while (bw) {
                    int j0 = __ffsll(bw) - 1; bw &= bw - 1;
                    int v1 = (bw != 0ull);
                    int j1 = v1 ? (__ffsll(bw) - 1) : j0;
                    if (v1) bw &= bw - 1;
                    int j = hsel ? j1 : j0;
                    int ls = w64 * 64 + j;
                    float c = s_t[ls];
                    if (hsel & (v1 ^ 1)) c = 0.f;
                    f32x4 xv = *(const f32x4*)&xh_t[ls][lx * 4];
                    acc[g2] += c * xv;
                }
            }
        }
    }
    __syncthreads();
    if (lane < 32) *(f32x4*)&red[wv][lx * 4] = csum;
    __syncthreads();
    f32x4 cs = (f32x4){0.f, 0.f, 0.f, 0.f};
    #pragma unroll
    for (int w2 = 0; w2 < 8; ++w2) cs += *(const f32x4*)&red[w2][lx * 4];
    cs *= 0.125f;

    float* out_b = heg + (size_t)bh * (PP * EE);
    #pragma unroll
    for (int g2 = 0; g2 < 16; ++g2) {
        f32x4 o = acc[g2];
        o.x += __shfl_xor(o.x, 32); o.y += __shfl_xor(o.y, 32);
        o.z += __shfl_xor(o.z, 32); o.w += __shfl_xor(o.w, 32);
        if (lane < 32) {
            int p = ph * 128 + wv * 16 + g2;
            *(f32x4*)&out_b[(size_t)p * 128 + lx * 4] = gelu4(cs + o);
        }
    }
}

// ---------------- k3b: ev[n,p,h] = exp(gelu(he_row)@W4[:128])
__global__ __launch_bounds__(256) void k3b_ev(const float* __restrict__ he,
                                              const float* __restrict__ W4,
                                              float* __restrict__ ev) {
    int tid = threadIdx.x, lane = tid & 63, wv = tid >> 6;
    size_t R = (size_t)blockIdx.x * 8 + wv * 2 + (lane >> 5);
    int lx = lane & 31;
    f32x4 v = *(const f32x4*)(he + R * 128 + lx * 4);
    f32x4 w = *(const f32x4*)(W4 + lx * 4);
    f32x4 gv = gelu4(v);
    float ae = gv.x * w.x + gv.y * w.y + gv.z * w.z + gv.w * w.w;
    ae += __shfl_xor(ae, 1); ae += __shfl_xor(ae, 2); ae += __shfl_xor(ae, 4);
    ae += __shfl_xor(ae, 8); ae += __shfl_xor(ae, 16);
    if (lx == 0) {
        int n = (int)(R >> 11), h = (int)((R >> 8) & 7), p = (int)(R & 255);
        ev[((size_t)(n * 256 + p)) * 8 + h] = expf(ae);
    }
}

// ---------------- k4: rdinv CSR: rd[n*512+l][slot] = 1/den(l,p) for set bits in ffs order (h-shared)
__global__ __launch_bounds__(256) void k4_rdinv(const float* __restrict__ eu,
                                                const float* __restrict__ ev,
                                                const unsigned* __restrict__ bits,
                                                float* __restrict__ rd) {
    __shared__ float ev_t[256][8];
    int b = blockIdx.x;
    int n = b >> 4, l0 = (b & 15) * 32;
    int tid = threadIdx.x, lane = tid & 63, wv = tid >> 6;
    {
        const f32x4* src = (const f32x4*)(ev + (size_t)n * 2048);
        f32x4* dst = (f32x4*)&ev_t[0][0];
        dst[tid] = src[tid];
        dst[tid + 256] = src[tid + 256];
    }
    __syncthreads();
    for (int i = 0; i < 8; ++i) {
        int l = l0 + wv * 8 + i;
        size_t rowg = (size_t)n * 512 + l;
        const float* eup = eu + rowg * 8;
        f32x4 ea = *(const f32x4*)eup;
        f32x4 eb = *(const f32x4*)(eup + 4);
        const unsigned* bp = bits + rowg * 8;
        int scnt = 0;
        #pragma unroll
        for (int w64 = 0; w64 < 4; ++w64) {
            int p = w64 * 64 + lane;
            f32x4 va = *(const f32x4*)&ev_t[p][0];
            f32x4 vb = *(const f32x4*)&ev_t[p][4];
            float den = ea.x * va.x + ea.y * va.y + ea.z * va.z + ea.w * va.w
                      + eb.x * vb.x + eb.y * vb.y + eb.z * vb.z + eb.w * vb.w;
            float r = rcp_f(den);
            r = r * (2.0f - den * r);
            unsigned word = bp[w64 * 2 + (lane >> 5)];
            int bitset = (word >> (lane & 31)) & 1;
            unsigned long long mask = __ballot(bitset != 0);
            unsigned long long lt = (lane == 0) ? 0ull : (~0ull >> (64 - lane));
            int slot = scnt + __popcll(mask & lt);
            if (bitset && slot < 64) rd[rowg * 64 + slot] = r;
            scnt += __popcll(mask);
        }
    }
}

// ---------------- K5 (sparse, bit-pair + CSR rdinv): x_nodes = 0.125*colsum_he + sum_{p} c*he[p,:]
__global__ __launch_bounds__(512) void k5_node_sparse(const float* __restrict__ he,
                                                      const float* __restrict__ eu,
                                                      const float* __restrict__ ev,
                                                      const unsigned* __restrict__ bits,
                                                      const unsigned* __restrict__ flags,
                                                      const float* __restrict__ rd,
                                                      const float* __restrict__ x,
                                                      float* __restrict__ out) {
    __shared__ float he_t[256][128];     // 128 KB
    __shared__ float euh_t[256];
    __shared__ float evh_t[256];
    __shared__ unsigned bt[256][8];      // 8 KB
    __shared__ float red[8][128];        // 4 KB
    int blk = blockIdx.x;
    int lh  = blk & 1;
    int bh  = blk >> 1;
    int n   = bh >> 3, h = bh & 7;
    int tid = threadIdx.x, lane = tid & 63, wv = tid >> 6;
    int lx = lane & 31, hsel = lane >> 5;
    {
        const f32x4* src = (const f32x4*)(he + (size_t)bh * (PP * EE));
        f32x4* dst = (f32x4*)&he_t[0][0];
        #pragma unroll
        for (int k = 0; k < 16; ++k) dst[tid + k * 512] = src[tid + k * 512];
        if (tid < 256) {
            euh_t[tid] = eu[((size_t)(n * 512 + lh * 256 + tid)) * 8 + h];
            evh_t[tid] = ev[((size_t)(n * 256 + tid)) * 8 + h];
        }
        ((uint4*)bt)[tid] = ((const uint4*)(bits + ((size_t)(n * 512 + lh * 256)) * 8))[tid];
    }
    __syncthreads();
    f32x4 csum = (f32x4){0.f, 0.f, 0.f, 0.f};
    #pragma unroll
    for (int r = 0; r < 32; ++r) csum += *(const f32x4*)&he_t[wv * 32 + r][lx * 4];
    if (lane < 32) *(f32x4*)&red[wv][lx * 4] = csum;
    __syncthreads();
    f32x4 cs = (f32x4){0.f, 0.f, 0.f, 0.f};
    #pragma unroll
    for (int w2 = 0; w2 < 8; ++w2) cs += *(const f32x4*)&red[w2][lx * 4];
    cs *= 0.125f;

    int rowg0 = n * 512 + lh * 256 + wv * 32;
    float rdcur = rd[(size_t)rowg0 * 64 + lane];
    for (int i = 0; i < 32; ++i) {
        int lrow = wv * 32 + i;
        int rowg = rowg0 + i;
        float rdnext = (i < 31) ? rd[(size_t)(rowg + 1) * 64 + lane] : 0.f;
        float euh = euh_t[lrow];
        f32x4 acc = (f32x4){0.f, 0.f, 0.f, 0.f};
        int scnt = 0;
        #pragma unroll
        for (int w64 = 0; w64 < 4; ++w64) {
            unsigned long long bw = bt[lrow][w64 * 2] | ((unsigned long long)bt[lrow][w64 * 2 + 1] << 32);
            while (bw) {
                int j0 = __ffsll(bw) - 1; bw &= bw - 1;
                int v1 = (bw != 0ull);
                int j1 = v1 ? (__ffsll(bw) - 1) : j0;
                if (v1) bw &= bw - 1;
                int j = hsel ? j1 : j0;
                int p = w64 * 64 + j;
                int slot = scnt + hsel;
                scnt += 1 + v1;
                int ri = __builtin_amdgcn_ds_bpermute(slot << 2, __float_as_int(rdcur));
                float rdv = __int_as_float(ri);
                float evv = evh_t[p];
                float c = euh * evv * rdv - 0.125f;
                if (hsel & (v1 ^ 1)) c = 0.f;
                f32x4 hv = *(const f32x4*)&he_t[p][lx * 4];
                acc += c * hv;
            }
        }
        acc.x += __shfl_xor(acc.x, 32); acc.y += __shfl_xor(acc.y, 32);
        acc.z += __shfl_xor(acc.z, 32); acc.w += __shfl_xor(acc.w, 32);
        int l = lh * 256 + lrow;
        if (lane < 32) {
            size_t o = ((size_t)(n * 512 + l)) * 1024 + h * 128 + lx * 4;
            if (flags[n * 512 + l]) {
                *(f32x4*)(out + o) = *(const f32x4*)(x + o);
            } else {
                *(f32x4*)(out + o) = gelu4(cs + acc);
            }
        }
        rdcur = rdnext;
    }
}

extern "C" void kernel_launch(void* const* d_in, const int* in_sizes, int n_in,
                              void* d_out, int out_size, void* d_ws, size_t ws_size,
                              hipStream_t stream) {
    (void)in_sizes; (void)n_in; (void)out_size; (void)ws_size;
    const float* x   = (const float*)d_in[0];
    const float* adj = (const float*)d_in[1];
    const float* W1  = (const float*)d_in[2];
    const float* b1  = (const float*)d_in[3];
    const float* W2  = (const float*)d_in[4];
    const float* W3  = (const float*)d_in[6];
    const float* b3  = (const float*)d_in[7];
    const float* W4  = (const float*)d_in[8];
    float* out = (float*)d_out;

    char* ws = (char*)d_ws;
    size_t off = 0;
    auto alloc = [&](size_t bytes) -> void* {
        void* p = ws + off;
        off += (bytes + 255) & ~(size_t)255;
        return p;
    };
    float* xh   = (float*)alloc((size_t)NB * LL * HH * EE * 4);   // 67 MB  [(n,l,h),e]
    float* s    = (float*)alloc((size_t)NB * HH * LL * 4);
    float* eu   = (float*)alloc((size_t)NB * LL * HH * 4);
    float* ev   = (float*)alloc((size_t)NB * PP * HH * 4);
    float* heg  = (float*)alloc((size_t)NB * HH * PP * EE * 4);   // 33.5 MB [(n,h,p),e]
    float* he   = (float*)alloc((size_t)NB * HH * PP * EE * 4);   // 33.5 MB
    float* rd   = (float*)alloc((size_t)NB * LL * 64 * 4);        // 4.2 MB CSR rdinv
    unsigned* bits  = (unsigned*)alloc((size_t)NB * LL * 8 * 4);
    unsigned* bitsT = (unsigned*)alloc((size_t)NB * PP * 16 * 4);
    unsigned* flags = (unsigned*)alloc((size_t)NB * LL * 4);
    unsigned short* W1h = (unsigned short*)alloc(16384 * 2);
    unsigned short* W1l = (unsigned short*)alloc(16384 * 2);
    unsigned short* W3h = (unsigned short*)alloc(16384 * 2);
    unsigned short* W3l = (unsigned short*)alloc(16384 * 2);

    hipLaunchKernelGGL(kpack, dim3(2), dim3(256), 0, stream, W1, W3, W1h, W1l, W3h, W3l);
    hipLaunchKernelGGL(k0_bits, dim3(NB * 8), dim3(256), 0, stream, adj, bits, bitsT, flags);
    hipLaunchKernelGGL(gemm128, dim3(1024), dim3(256), 0, stream, x, W1h, W1l, b1, xh);
    hipLaunchKernelGGL(k1b_softmax, dim3(4096), dim3(256), 0, stream, xh, W2, W4, s, eu);
    hipLaunchKernelGGL(k2_edge_sparse, dim3(NB * HH * 2), dim3(512), 0, stream, xh, s, bitsT, heg);
    hipLaunchKernelGGL(gemm128, dim3(512), dim3(256), 0, stream, heg, W3h, W3l, b3, he);
    hipLaunchKernelGGL(k3b_ev, dim3(8192), dim3(256), 0, stream, he, W4, ev);
    hipLaunchKernelGGL(k4_rdinv, dim3(NB * 16), dim3(256), 0, stream, eu, ev, bits, rd);
    hipLaunchKernelGGL(k5_node_sparse, dim3(NB * HH * 2), dim3(512), 0, stream, he, eu, ev, bits, flags, rd, x, out);
}

// Round 4
// 360.989 us; speedup vs baseline: 1.7876x; 1.3468x over previous
//
#include <hip/hip_runtime.h>
#include <math.h>

#define NB 32
#define LL 512
#define PP 256
#define HH 8
#define EE 128
#define DD 1024

typedef __attribute__((ext_vector_type(4))) float f32x4;
typedef __attribute__((ext_vector_type(8))) short short8;

__device__ __forceinline__ float gelu_f(float v) {
    return 0.5f * v * (1.0f + erff(v * 0.70710678118654752f));
}
__device__ __forceinline__ float rcp_f(float v) {
    float r; asm("v_rcp_f32 %0, %1" : "=v"(r) : "v"(v)); return r;
}
__device__ __forceinline__ unsigned short bf16_rne(float v) {
    unsigned u = __float_as_uint(v);
    unsigned r = u + 0x7FFFu + ((u >> 16) & 1u);
    return (unsigned short)(r >> 16);
}
__device__ __forceinline__ float bf2f(short s) {
    return __uint_as_float(((unsigned)(unsigned short)s) << 16);
}
__device__ __forceinline__ f32x4 gelu4(f32x4 v) {
    f32x4 g; g.x = gelu_f(v.x); g.y = gelu_f(v.y); g.z = gelu_f(v.z); g.w = gelu_f(v.w); return g;
}

// ---------------- kpack: W (128x128 fp32) -> bf16 hi/lo in MFMA B-fragment order
__global__ __launch_bounds__(256) void kpack(const float* __restrict__ W1,
                                             const float* __restrict__ W3,
                                             unsigned short* __restrict__ W1h,
                                             unsigned short* __restrict__ W1l,
                                             unsigned short* __restrict__ W3h,
                                             unsigned short* __restrict__ W3l) {
    const float* W = blockIdx.x ? W3 : W1;
    unsigned short* Ph = blockIdx.x ? W3h : W1h;
    unsigned short* Pl = blockIdx.x ? W3l : W1l;
    for (int i = threadIdx.x; i < 16384; i += 256) {
        int oct = i >> 10, col = (i >> 3) & 127, j = i & 7;
        float v = W[(oct * 8 + j) * 128 + col];
        unsigned short hb = bf16_rne(v);
        float hf = __uint_as_float((unsigned)hb << 16);
        Ph[i] = hb;
        Pl[i] = bf16_rne(v - hf);
    }
}

// ---------------- K0: pack mask to bits (row-major + col-major) + no-edge flags
__global__ __launch_bounds__(256) void k0_bits(const float* __restrict__ adj,
                                               unsigned* __restrict__ bits,
                                               unsigned* __restrict__ bitsT,
                                               unsigned* __restrict__ flags) {
    __shared__ unsigned lbits[64][8];
    int n  = blockIdx.x >> 3;
    int l0 = (blockIdx.x & 7) * 64;
    int lane = threadIdx.x & 63;
    int wv   = threadIdx.x >> 6;
    for (int r = wv; r < 64; r += 4) {
        int l = l0 + r;
        const float* row = adj + ((size_t)n * LL + l) * PP;
        int cnt = 0;
        for (int c = 0; c < 4; ++c) {
            float v = row[c * 64 + lane];
            unsigned long long b = __ballot(v != 0.0f);
            if (lane == 0) {
                lbits[r][c * 2]     = (unsigned)b;
                lbits[r][c * 2 + 1] = (unsigned)(b >> 32);
                cnt += __popcll(b);
            }
        }
        if (lane == 0) {
            flags[n * LL + l] = (cnt == 0) ? 1u : 0u;
            for (int w = 0; w < 8; ++w)
                bits[((size_t)n * LL + l) * 8 + w] = lbits[r][w];
        }
    }
    __syncthreads();
    int p = threadIdx.x;
    unsigned w0 = 0, w1 = 0;
    int wp = p >> 5, bp = p & 31;
    for (int j = 0; j < 32; ++j) {
        w0 |= ((lbits[j][wp] >> bp) & 1u) << j;
        w1 |= ((lbits[j + 32][wp] >> bp) & 1u) << j;
    }
    bitsT[((size_t)n * PP + p) * 16 + (l0 >> 5)]     = w0;
    bitsT[((size_t)n * PP + p) * 16 + (l0 >> 5) + 1] = w1;
}

// ---------------- gemm128: C[M x 128] = A[M x 128] @ W[128 x 128] + bias (3-pass split bf16)
__global__ __launch_bounds__(256) void gemm128(const float* __restrict__ A,
                                               const unsigned short* __restrict__ Bhi,
                                               const unsigned short* __restrict__ Blo,
                                               const float* __restrict__ bias,
                                               float* __restrict__ C) {
    int tid = threadIdx.x, lane = tid & 63, w = tid >> 6;
    size_t rowbase = (size_t)blockIdx.x * 128 + w * 32;
    int rl = lane & 15, g = lane >> 4;
    f32x4 acc[2][8];
    #pragma unroll
    for (int t = 0; t < 2; ++t)
        #pragma unroll
        for (int nt = 0; nt < 8; ++nt) acc[t][nt] = (f32x4){0.f, 0.f, 0.f, 0.f};

    #pragma unroll
    for (int kc = 0; kc < 4; ++kc) {
        short8 ah[2], al[2];
        #pragma unroll
        for (int t = 0; t < 2; ++t) {
            const float* ap = A + (rowbase + t * 16 + rl) * 128 + kc * 32 + g * 8;
            f32x4 a0 = *(const f32x4*)ap;
            f32x4 a1 = *(const f32x4*)(ap + 4);
            float av[8] = {a0.x, a0.y, a0.z, a0.w, a1.x, a1.y, a1.z, a1.w};
            #pragma unroll
            for (int j = 0; j < 8; ++j) {
                unsigned short hb = bf16_rne(av[j]);
                float hf = __uint_as_float((unsigned)hb << 16);
                ah[t][j] = (short)hb;
                al[t][j] = (short)bf16_rne(av[j] - hf);
            }
        }
        #pragma unroll
        for (int nt = 0; nt < 8; ++nt) {
            int oct = kc * 4 + g, col = nt * 16 + rl;
            short8 bh = *(const short8*)(Bhi + ((size_t)(oct * 128 + col)) * 8);
            short8 bl = *(const short8*)(Blo + ((size_t)(oct * 128 + col)) * 8);
            #pragma unroll
            for (int t = 0; t < 2; ++t) {
                acc[t][nt] = __builtin_amdgcn_mfma_f32_16x16x32_bf16(ah[t], bh, acc[t][nt], 0, 0, 0);
                acc[t][nt] = __builtin_amdgcn_mfma_f32_16x16x32_bf16(ah[t], bl, acc[t][nt], 0, 0, 0);
                acc[t][nt] = __builtin_amdgcn_mfma_f32_16x16x32_bf16(al[t], bh, acc[t][nt], 0, 0, 0);
            }
        }
    }
    #pragma unroll
    for (int nt = 0; nt < 8; ++nt) {
        int col = nt * 16 + rl;
        float bv = bias[col];
        #pragma unroll
        for (int t = 0; t < 2; ++t)
            #pragma unroll
            for (int r = 0; r < 4; ++r) {
                size_t row = rowbase + t * 16 + g * 4 + r;
                C[row * 128 + col] = acc[t][nt][r] + bv;
            }
    }
}

// ---------------- gemm128_heT: gemm128 + LDS-transpose epilogue writing heT bf16 [(n,h)][e][p]
__global__ __launch_bounds__(256) void gemm128_heT(const float* __restrict__ A,
                                                   const unsigned short* __restrict__ Bhi,
                                                   const unsigned short* __restrict__ Blo,
                                                   const float* __restrict__ bias,
                                                   float* __restrict__ C,
                                                   unsigned short* __restrict__ heT) {
    __shared__ __align__(16) unsigned short tbuf[128 * 128];  // swizzled [e][p_local]
    int tid = threadIdx.x, lane = tid & 63, w = tid >> 6;
    size_t rowbase = (size_t)blockIdx.x * 128 + w * 32;
    int rl = lane & 15, g = lane >> 4;
    f32x4 acc[2][8];
    #pragma unroll
    for (int t = 0; t < 2; ++t)
        #pragma unroll
        for (int nt = 0; nt < 8; ++nt) acc[t][nt] = (f32x4){0.f, 0.f, 0.f, 0.f};

    #pragma unroll
    for (int kc = 0; kc < 4; ++kc) {
        short8 ah[2], al[2];
        #pragma unroll
        for (int t = 0; t < 2; ++t) {
            const float* ap = A + (rowbase + t * 16 + rl) * 128 + kc * 32 + g * 8;
            f32x4 a0 = *(const f32x4*)ap;
            f32x4 a1 = *(const f32x4*)(ap + 4);
            float av[8] = {a0.x, a0.y, a0.z, a0.w, a1.x, a1.y, a1.z, a1.w};
            #pragma unroll
            for (int j = 0; j < 8; ++j) {
                unsigned short hb = bf16_rne(av[j]);
                float hf = __uint_as_float((unsigned)hb << 16);
                ah[t][j] = (short)hb;
                al[t][j] = (short)bf16_rne(av[j] - hf);
            }
        }
        #pragma unroll
        for (int nt = 0; nt < 8; ++nt) {
            int oct = kc * 4 + g, col = nt * 16 + rl;
            short8 bh = *(const short8*)(Bhi + ((size_t)(oct * 128 + col)) * 8);
            short8 bl = *(const short8*)(Blo + ((size_t)(oct * 128 + col)) * 8);
            #pragma unroll
            for (int t = 0; t < 2; ++t) {
                acc[t][nt] = __builtin_amdgcn_mfma_f32_16x16x32_bf16(ah[t], bh, acc[t][nt], 0, 0, 0);
                acc[t][nt] = __builtin_amdgcn_mfma_f32_16x16x32_bf16(ah[t], bl, acc[t][nt], 0, 0, 0);
                acc[t][nt] = __builtin_amdgcn_mfma_f32_16x16x32_bf16(al[t], bh, acc[t][nt], 0, 0, 0);
            }
        }
    }
    #pragma unroll
    for (int nt = 0; nt < 8; ++nt) {
        int col = nt * 16 + rl;
        float bv = bias[col];
        #pragma unroll
        for (int t = 0; t < 2; ++t) {
            float v0 = acc[t][nt][0] + bv;
            float v1 = acc[t][nt][1] + bv;
            float v2 = acc[t][nt][2] + bv;
            float v3 = acc[t][nt][3] + bv;
            size_t row = rowbase + t * 16 + g * 4;
            C[row * 128 + col]       = v0;
            C[(row + 1) * 128 + col] = v1;
            C[(row + 2) * 128 + col] = v2;
            C[(row + 3) * 128 + col] = v3;
            int row_loc = w * 32 + t * 16 + g * 4;
            int byte = (col * 256 + row_loc * 2) ^ ((col & 7) << 4);
            *(ushort4*)((char*)tbuf + byte) =
                make_ushort4(bf16_rne(v0), bf16_rne(v1), bf16_rne(v2), bf16_rne(v3));
        }
    }
    __syncthreads();
    int bh2 = blockIdx.x >> 1, p0 = (blockIdx.x & 1) * 128;
    #pragma unroll
    for (int rep = 0; rep < 8; ++rep) {
        int id = rep * 256 + tid;
        int e = id >> 4, j = id & 15;
        int byte = (e * 256 + j * 16) ^ ((e & 7) << 4);
        short8 v = *(const short8*)((char*)tbuf + byte);
        *(short8*)(heT + (size_t)bh2 * 32768 + (size_t)e * 256 + p0 + j * 8) = v;
    }
}

// ---------------- k1b: s = softmax_h(gelu(xh)@W2), eu = exp(a_node - max_h)
__global__ __launch_bounds__(256) void k1b_softmax(const float* __restrict__ xh,
                                                   const float* __restrict__ W2,
                                                   const float* __restrict__ W4,
                                                   float* __restrict__ s_out,
                                                   float* __restrict__ eu) {
    int tid = threadIdx.x, lane = tid & 63, wv = tid >> 6;
    int base = blockIdx.x * 4 + wv;
    int n = base >> 9, l = base & 511;
    int h = lane >> 3, sub = lane & 7;
    const float* xp = xh + (size_t)base * 1024 + h * 128 + sub * 16;
    float xv = 0.f, an = 0.f;
    #pragma unroll
    for (int q = 0; q < 4; ++q) {
        f32x4 v  = *(const f32x4*)(xp + q * 4);
        f32x4 w2 = *(const f32x4*)(W2 + sub * 16 + q * 4);
        f32x4 w4 = *(const f32x4*)(W4 + 128 + sub * 16 + q * 4);
        f32x4 gv = gelu4(v);
        xv += gv.x * w2.x + gv.y * w2.y + gv.z * w2.z + gv.w * w2.w;
        an += gv.x * w4.x + gv.y * w4.y + gv.z * w4.z + gv.w * w4.w;
    }
    xv += __shfl_xor(xv, 1); xv += __shfl_xor(xv, 2); xv += __shfl_xor(xv, 4);
    an += __shfl_xor(an, 1); an += __shfl_xor(an, 2); an += __shfl_xor(an, 4);
    float mx = xv;
    mx = fmaxf(mx, __shfl_xor(mx, 8)); mx = fmaxf(mx, __shfl_xor(mx, 16)); mx = fmaxf(mx, __shfl_xor(mx, 32));
    float ex = expf(xv - mx);
    float sm = ex;
    sm += __shfl_xor(sm, 8); sm += __shfl_xor(sm, 16); sm += __shfl_xor(sm, 32);
    float sv = ex / sm;
    float mxa = an;
    mxa = fmaxf(mxa, __shfl_xor(mxa, 8)); mxa = fmaxf(mxa, __shfl_xor(mxa, 16)); mxa = fmaxf(mxa, __shfl_xor(mxa, 32));
    float euv = expf(an - mxa);
    if (sub == 0) {
        s_out[((size_t)(n * 8 + h)) * 512 + l] = sv;
        eu[(size_t)base * 8 + h] = euv;
    }
}

// ---------------- K2 (sparse, bit-pair): heg[p,e] = gelu(0.125*colsum + sum_{l in bits(p)} (s[l]-0.125)*xh[l,e])
__global__ __launch_bounds__(512) void k2_edge_sparse(const float* __restrict__ xh,
                                                      const float* __restrict__ s_in,
                                                      const unsigned* __restrict__ bitsT,
                                                      float* __restrict__ heg) {
    __shared__ float xh_t[128][128];
    __shared__ float s_t[128];
    __shared__ unsigned bT[128][4];
    __shared__ float red[8][128];
    int blk = blockIdx.x;
    int ph  = blk & 1;
    int bh  = blk >> 1;
    int n   = bh >> 3, h = bh & 7;
    int tid = threadIdx.x, lane = tid & 63, wv = tid >> 6;
    int lx = lane & 31, hsel = lane >> 5;

    f32x4 acc[16];
    #pragma unroll
    for (int g2 = 0; g2 < 16; ++g2) acc[g2] = (f32x4){0.f, 0.f, 0.f, 0.f};
    f32x4 csum = (f32x4){0.f, 0.f, 0.f, 0.f};

    for (int lt = 0; lt < 4; ++lt) {
        __syncthreads();
        #pragma unroll
        for (int pass = 0; pass < 8; ++pass) {
            int r = pass * 16 + (tid >> 5);
            *(f32x4*)&xh_t[r][(tid & 31) * 4] =
                *(const f32x4*)(xh + (((size_t)(n * 512 + lt * 128 + r)) * 8 + h) * 128 + (tid & 31) * 4);
        }
        if (tid < 128) s_t[tid] = s_in[(size_t)bh * 512 + lt * 128 + tid] - 0.125f;
        { int p = ph * 128 + (tid >> 2);
          bT[tid >> 2][tid & 3] = bitsT[((size_t)(n * 256 + p)) * 16 + lt * 4 + (tid & 3)]; }
        __syncthreads();
        #pragma unroll
        for (int r = 0; r < 16; ++r) csum += *(const f32x4*)&xh_t[wv * 16 + r][lx * 4];
        #pragma unroll
        for (int g2 = 0; g2 < 16; ++g2) {
            int prow = wv * 16 + g2;
            #pragma unroll
            for (int w64 = 0; w64 < 2; ++w64) {
                unsigned long long bw = bT[prow][w64 * 2] | ((unsigned long long)bT[prow][w64 * 2 + 1] << 32);
                while (bw) {
                    int j0 = __ffsll(bw) - 1; bw &= bw - 1;
                    int v1 = (bw != 0ull);
                    int j1 = v1 ? (__ffsll(bw) - 1) : j0;
                    if (v1) bw &= bw - 1;
                    int j = hsel ? j1 : j0;
                    int ls = w64 * 64 + j;
                    float c = s_t[ls];
                    if (hsel & (v1 ^ 1)) c = 0.f;
                    f32x4 xv = *(const f32x4*)&xh_t[ls][lx * 4];
                    acc[g2] += c * xv;
                }
            }
        }
    }
    __syncthreads();
    if (lane < 32) *(f32x4*)&red[wv][lx * 4] = csum;
    __syncthreads();
    f32x4 cs = (f32x4){0.f, 0.f, 0.f, 0.f};
    #pragma unroll
    for (int w2 = 0; w2 < 8; ++w2) cs += *(const f32x4*)&red[w2][lx * 4];
    cs *= 0.125f;

    float* out_b = heg + (size_t)bh * (PP * EE);
    #pragma unroll
    for (int g2 = 0; g2 < 16; ++g2) {
        f32x4 o = acc[g2];
        o.x += __shfl_xor(o.x, 32); o.y += __shfl_xor(o.y, 32);
        o.z += __shfl_xor(o.z, 32); o.w += __shfl_xor(o.w, 32);
        if (lane < 32) {
            int p = ph * 128 + wv * 16 + g2;
            *(f32x4*)&out_b[(size_t)p * 128 + lx * 4] = gelu4(cs + o);
        }
    }
}

// ---------------- k3b: ev[n,p,h] = exp(gelu(he_row)@W4[:E])
__global__ __launch_bounds__(256) void k3b_ev(const float* __restrict__ he,
                                              const float* __restrict__ W4,
                                              float* __restrict__ ev) {
    int tid = threadIdx.x, lane = tid & 63, wv = tid >> 6;
    size_t R = (size_t)blockIdx.x * 8 + wv * 2 + (lane >> 5);
    int lx = lane & 31;
    f32x4 v = *(const f32x4*)(he + R * 128 + lx * 4);
    f32x4 w = *(const f32x4*)(W4 + lx * 4);
    f32x4 gv = gelu4(v);
    float ae = gv.x * w.x + gv.y * w.y + gv.z * w.z + gv.w * w.w;
    ae += __shfl_xor(ae, 1); ae += __shfl_xor(ae, 2); ae += __shfl_xor(ae, 4);
    ae += __shfl_xor(ae, 8); ae += __shfl_xor(ae, 16);
    if (lx == 0) {
        int n = (int)(R >> 11), h = (int)((R >> 8) & 7), p = (int)(R & 255);
        ev[((size_t)(n * 256 + p)) * 8 + h] = expf(ae);
    }
}

// ---------------- k4_dense: rdm[n][l][p] = bit ? 1/den : 0  (bf16, h-shared)
__global__ __launch_bounds__(256) void k4_dense(const float* __restrict__ eu,
                                                const float* __restrict__ ev,
                                                const unsigned* __restrict__ bits,
                                                unsigned short* __restrict__ rdm) {
    __shared__ float ev_t[256][8];
    int b = blockIdx.x;
    int n = b >> 3, l0 = (b & 7) * 64;
    int tid = threadIdx.x;
    {
        const f32x4* src = (const f32x4*)(ev + (size_t)n * 2048);
        f32x4* dst = (f32x4*)&ev_t[0][0];
        dst[tid] = src[tid];
        dst[tid + 256] = src[tid + 256];
    }
    __syncthreads();
    int l = l0 + (tid >> 2), pq = tid & 3;
    size_t rowg = (size_t)n * 512 + l;
    f32x4 ea = *(const f32x4*)(eu + rowg * 8);
    f32x4 eb = *(const f32x4*)(eu + rowg * 8 + 4);
    unsigned w0 = bits[rowg * 8 + pq * 2], w1 = bits[rowg * 8 + pq * 2 + 1];
    for (int c = 0; c < 8; ++c) {
        short8 o8;
        #pragma unroll
        for (int k = 0; k < 8; ++k) {
            int pl = c * 8 + k;
            int p = pq * 64 + pl;
            f32x4 va = *(const f32x4*)&ev_t[p][0];
            f32x4 vb = *(const f32x4*)&ev_t[p][4];
            float den = ea.x * va.x + ea.y * va.y + ea.z * va.z + ea.w * va.w
                      + eb.x * vb.x + eb.y * vb.y + eb.z * vb.z + eb.w * vb.w;
            unsigned bit = (pl < 32) ? ((w0 >> pl) & 1u) : ((w1 >> (pl - 32)) & 1u);
            float r = bit ? rcp_f(den) : 0.0f;
            o8[k] = (short)bf16_rne(r);
        }
        *(short8*)(rdm + rowg * 256 + pq * 64 + c * 8) = o8;
    }
}

// ---------------- k5_mfma: x_nodes = 0.125*colsum(he) + A @ he ; A[l,p] = bit ? att-0.125 : 0 (bf16)
__global__ __launch_bounds__(512) void k5_mfma(const unsigned short* __restrict__ heT,
                                               const unsigned short* __restrict__ rdm,
                                               const float* __restrict__ eu,
                                               const float* __restrict__ ev,
                                               const unsigned* __restrict__ flags,
                                               const float* __restrict__ x,
                                               float* __restrict__ out) {
    __shared__ __align__(16) unsigned short heT_s[128 * 256];  // swizzled [e][p], 64 KB
    __shared__ __align__(16) unsigned short A_s[64 * 256];     // swizzled [l_loc][p], 32 KB
    __shared__ float evh_s[256];
    __shared__ float euh_s[64];
    __shared__ float cs_s[128];
    __shared__ float csr_s[4][128];
    __shared__ unsigned flg_s[64];

    int bid = blockIdx.x;
    int xcd = bid & 7, slot = bid >> 3;          // group 8 heads of same n per XCD (rdm L2 reuse)
    int n = xcd * 4 + (slot & 3), h = slot >> 2;
    int bh = n * 8 + h;
    int tid = threadIdx.x, lane = tid & 63, w = tid >> 6;

    // stage heT (swizzled) + evh
    const unsigned short* hb = heT + (size_t)bh * 32768;
    #pragma unroll
    for (int i = 0; i < 8; ++i) {
        int id = tid + i * 512;
        int e = id >> 5, jj = id & 31;
        short8 v = *(const short8*)(hb + e * 256 + jj * 8);
        *(short8*)((char*)heT_s + ((e * 512 + jj * 16) ^ ((e & 7) << 4))) = v;
    }
    if (tid < 256) evh_s[tid] = ev[((size_t)(n * 256 + tid)) * 8 + h];
    __syncthreads();
    // colsum over p (fp32)
    {
        int e = tid & 127, q = tid >> 7;
        float a = 0.f;
        #pragma unroll
        for (int j = 0; j < 8; ++j) {
            int byte = (e * 512 + (q * 64 + j * 8) * 2) ^ ((e & 7) << 4);
            short8 v = *(const short8*)((char*)heT_s + byte);
            #pragma unroll
            for (int k = 0; k < 8; ++k) a += bf2f(v[k]);
        }
        csr_s[q][e] = a;
    }
    __syncthreads();
    if (tid < 128) cs_s[tid] = 0.125f * (csr_s[0][tid] + csr_s[1][tid] + csr_s[2][tid] + csr_s[3][tid]);

    int rl = lane & 15, g = lane >> 4;
    int wm = w & 1, wn = w >> 1;          // wave -> 2mt x 2nt tile group
    int swz = (rl & 7) << 4;

    for (int lt = 0; lt < 8; ++lt) {
        int l0 = lt * 64;
        if (tid < 64) {
            euh_s[tid] = eu[((size_t)(n * 512 + l0 + tid)) * 8 + h];
            flg_s[tid] = flags[n * 512 + l0 + tid];
        }
        __syncthreads();
        // build A tile (64 x 256 bf16, swizzled)
        {
            int l_loc = tid >> 3, p0 = (tid & 7) * 32;
            float euh = euh_s[l_loc];
            const unsigned short* rp = rdm + ((size_t)(n * 512 + l0 + l_loc)) * 256 + p0;
            #pragma unroll
            for (int c = 0; c < 4; ++c) {
                short8 rv = *(const short8*)(rp + c * 8);
                short8 o8;
                #pragma unroll
                for (int k = 0; k < 8; ++k) {
                    unsigned u = (unsigned)(unsigned short)rv[k];
                    float rf = __uint_as_float(u << 16);
                    float m125 = (u != 0u) ? -0.125f : 0.0f;
                    float a = fmaf(euh * evh_s[p0 + c * 8 + k], rf, m125);
                    o8[k] = (short)bf16_rne(a);
                }
                *(short8*)((char*)A_s + ((l_loc * 512 + (p0 + c * 8) * 2) ^ ((l_loc & 7) << 4))) = o8;
            }
        }
        __syncthreads();
        // MFMA: C[64 x 128] += A[64 x 256] @ he[256 x 128]
        f32x4 acc[2][2];
        #pragma unroll
        for (int i = 0; i < 2; ++i)
            #pragma unroll
            for (int j = 0; j < 2; ++j) acc[i][j] = (f32x4){0.f, 0.f, 0.f, 0.f};
        #pragma unroll
        for (int kt = 0; kt < 8; ++kt) {
            short8 af[2], bfr[2];
            #pragma unroll
            for (int i = 0; i < 2; ++i) {
                int arow = (wm * 2 + i) * 16 + rl;
                af[i] = *(const short8*)((char*)A_s + ((arow * 512 + kt * 64 + g * 16) ^ swz));
                int e = (wn * 2 + i) * 16 + rl;
                bfr[i] = *(const short8*)((char*)heT_s + ((e * 512 + kt * 64 + g * 16) ^ swz));
            }
            acc[0][0] = __builtin_amdgcn_mfma_f32_16x16x32_bf16(af[0], bfr[0], acc[0][0], 0, 0, 0);
            acc[0][1] = __builtin_amdgcn_mfma_f32_16x16x32_bf16(af[0], bfr[1], acc[0][1], 0, 0, 0);
            acc[1][0] = __builtin_amdgcn_mfma_f32_16x16x32_bf16(af[1], bfr[0], acc[1][0], 0, 0, 0);
            acc[1][1] = __builtin_amdgcn_mfma_f32_16x16x32_bf16(af[1], bfr[1], acc[1][1], 0, 0, 0);
        }
        // epilogue
        #pragma unroll
        for (int i = 0; i < 2; ++i) {
            #pragma unroll
            for (int j = 0; j < 2; ++j) {
                int e = (wn * 2 + j) * 16 + rl;
                float csv = cs_s[e];
                #pragma unroll
                for (int r = 0; r < 4; ++r) {
                    int row = (wm * 2 + i) * 16 + g * 4 + r;
                    int l = l0 + row;
                    size_t addr = ((size_t)(n * 512 + l)) * 1024 + h * 128 + e;
                    if (flg_s[row]) {
                        out[addr] = x[addr];
                    } else {
                        out[addr] = gelu_f(acc[i][j][r] + csv);
                    }
                }
            }
        }
        __syncthreads();
    }
}

extern "C" void kernel_launch(void* const* d_in, const int* in_sizes, int n_in,
                              void* d_out, int out_size, void* d_ws, size_t ws_size,
                              hipStream_t stream) {
    (void)in_sizes; (void)n_in; (void)out_size; (void)ws_size;
    const float* x   = (const float*)d_in[0];
    const float* adj = (const float*)d_in[1];
    const float* W1  = (const float*)d_in[2];
    const float* b1  = (const float*)d_in[3];
    const float* W2  = (const float*)d_in[4];
    const float* W3  = (const float*)d_in[6];
    const float* b3  = (const float*)d_in[7];
    const float* W4  = (const float*)d_in[8];
    float* out = (float*)d_out;

    char* ws = (char*)d_ws;
    size_t off = 0;
    auto alloc = [&](size_t bytes) -> void* {
        void* p = ws + off;
        off += (bytes + 255) & ~(size_t)255;
        return p;
    };
    float* xh   = (float*)alloc((size_t)NB * LL * HH * EE * 4);        // 67 MB  [(n,l,h)][e]
    float* s    = (float*)alloc((size_t)NB * HH * LL * 4);
    float* eu   = (float*)alloc((size_t)NB * LL * HH * 4);
    float* ev   = (float*)alloc((size_t)NB * PP * HH * 4);
    float* heg  = (float*)alloc((size_t)NB * HH * PP * EE * 4);        // 33.5 MB [(n,h,p)][e]
    float* he   = (float*)alloc((size_t)NB * HH * PP * EE * 4);        // 33.5 MB
    unsigned short* heT = (unsigned short*)alloc((size_t)NB * HH * EE * PP * 2);  // 16.8 MB [(n,h)][e][p]
    unsigned short* rdm = (unsigned short*)alloc((size_t)NB * LL * PP * 2);       // 8.4 MB [n][l][p]
    unsigned* bits  = (unsigned*)alloc((size_t)NB * LL * 8 * 4);
    unsigned* bitsT = (unsigned*)alloc((size_t)NB * PP * 16 * 4);
    unsigned* flags = (unsigned*)alloc((size_t)NB * LL * 4);
    unsigned short* W1h = (unsigned short*)alloc(16384 * 2);
    unsigned short* W1l = (unsigned short*)alloc(16384 * 2);
    unsigned short* W3h = (unsigned short*)alloc(16384 * 2);
    unsigned short* W3l = (unsigned short*)alloc(16384 * 2);

    hipLaunchKernelGGL(kpack, dim3(2), dim3(256), 0, stream, W1, W3, W1h, W1l, W3h, W3l);
    hipLaunchKernelGGL(k0_bits, dim3(NB * 8), dim3(256), 0, stream, adj, bits, bitsT, flags);
    hipLaunchKernelGGL(gemm128, dim3(1024), dim3(256), 0, stream, x, W1h, W1l, b1, xh);
    hipLaunchKernelGGL(k1b_softmax, dim3(4096), dim3(256), 0, stream, xh, W2, W4, s, eu);
    hipLaunchKernelGGL(k2_edge_sparse, dim3(NB * HH * 2), dim3(512), 0, stream, xh, s, bitsT, heg);
    hipLaunchKernelGGL(gemm128_heT, dim3(512), dim3(256), 0, stream, heg, W3h, W3l, b3, he, heT);
    hipLaunchKernelGGL(k3b_ev, dim3(8192), dim3(256), 0, stream, he, W4, ev);
    hipLaunchKernelGGL(k4_dense, dim3(NB * 8), dim3(256), 0, stream, eu, ev, bits, rdm);
    hipLaunchKernelGGL(k5_mfma, dim3(NB * HH), dim3(512), 0, stream, heT, rdm, eu, ev, flags, x, out);
}

// Round 6
// 247.464 us; speedup vs baseline: 2.6077x; 1.4588x over previous
//
#include <hip/hip_runtime.h>
#include <math.h>

#define NB 32
#define LL 512
#define PP 256
#define HH 8
#define EE 128
#define DD 1024

typedef __attribute__((ext_vector_type(4))) float f32x4;
typedef __attribute__((ext_vector_type(8))) short short8;

__device__ __forceinline__ float gelu_f(float v) {
    return 0.5f * v * (1.0f + erff(v * 0.70710678118654752f));
}
__device__ __forceinline__ float rcp_f(float v) {
    float r; asm("v_rcp_f32 %0, %1" : "=v"(r) : "v"(v)); return r;
}
__device__ __forceinline__ unsigned short bf16_rne(float v) {
    unsigned u = __float_as_uint(v);
    unsigned r = u + 0x7FFFu + ((u >> 16) & 1u);
    return (unsigned short)(r >> 16);
}
__device__ __forceinline__ float bf2f(short s) {
    return __uint_as_float(((unsigned)(unsigned short)s) << 16);
}
__device__ __forceinline__ f32x4 gelu4(f32x4 v) {
    f32x4 g; g.x = gelu_f(v.x); g.y = gelu_f(v.y); g.z = gelu_f(v.z); g.w = gelu_f(v.w); return g;
}

// ---------------- kpack: W (128x128 fp32) -> bf16 hi/lo in MFMA B-fragment order
__global__ __launch_bounds__(256) void kpack(const float* __restrict__ W1,
                                             const float* __restrict__ W3,
                                             unsigned short* __restrict__ W1h,
                                             unsigned short* __restrict__ W1l,
                                             unsigned short* __restrict__ W3h,
                                             unsigned short* __restrict__ W3l) {
    const float* W = blockIdx.x ? W3 : W1;
    unsigned short* Ph = blockIdx.x ? W3h : W1h;
    unsigned short* Pl = blockIdx.x ? W3l : W1l;
    for (int i = threadIdx.x; i < 16384; i += 256) {
        int oct = i >> 10, col = (i >> 3) & 127, j = i & 7;
        float v = W[(oct * 8 + j) * 128 + col];
        unsigned short hb = bf16_rne(v);
        float hf = __uint_as_float((unsigned)hb << 16);
        Ph[i] = hb;
        Pl[i] = bf16_rne(v - hf);
    }
}

// ---------------- K0: pack mask to bits (row-major + col-major) + no-edge flags
__global__ __launch_bounds__(256) void k0_bits(const float* __restrict__ adj,
                                               unsigned* __restrict__ bits,
                                               unsigned* __restrict__ bitsT,
                                               unsigned* __restrict__ flags) {
    __shared__ unsigned lbits[64][8];
    int n  = blockIdx.x >> 3;
    int l0 = (blockIdx.x & 7) * 64;
    int lane = threadIdx.x & 63;
    int wv   = threadIdx.x >> 6;
    for (int r = wv; r < 64; r += 4) {
        int l = l0 + r;
        const float* row = adj + ((size_t)n * LL + l) * PP;
        int cnt = 0;
        for (int c = 0; c < 4; ++c) {
            float v = row[c * 64 + lane];
            unsigned long long b = __ballot(v != 0.0f);
            if (lane == 0) {
                lbits[r][c * 2]     = (unsigned)b;
                lbits[r][c * 2 + 1] = (unsigned)(b >> 32);
                cnt += __popcll(b);
            }
        }
        if (lane == 0) {
            flags[n * LL + l] = (cnt == 0) ? 1u : 0u;
            for (int w = 0; w < 8; ++w)
                bits[((size_t)n * LL + l) * 8 + w] = lbits[r][w];
        }
    }
    __syncthreads();
    int p = threadIdx.x;
    unsigned w0 = 0, w1 = 0;
    int wp = p >> 5, bp = p & 31;
    for (int j = 0; j < 32; ++j) {
        w0 |= ((lbits[j][wp] >> bp) & 1u) << j;
        w1 |= ((lbits[j + 32][wp] >> bp) & 1u) << j;
    }
    bitsT[((size_t)n * PP + p) * 16 + (l0 >> 5)]     = w0;
    bitsT[((size_t)n * PP + p) * 16 + (l0 >> 5) + 1] = w1;
}

// ---------------- gemm128: C[M x 128] = A[M x 128] @ W[128 x 128] + bias (3-pass split bf16)
__global__ __launch_bounds__(256) void gemm128(const float* __restrict__ A,
                                               const unsigned short* __restrict__ Bhi,
                                               const unsigned short* __restrict__ Blo,
                                               const float* __restrict__ bias,
                                               float* __restrict__ C) {
    int tid = threadIdx.x, lane = tid & 63, w = tid >> 6;
    size_t rowbase = (size_t)blockIdx.x * 128 + w * 32;
    int rl = lane & 15, g = lane >> 4;
    f32x4 acc[2][8];
    #pragma unroll
    for (int t = 0; t < 2; ++t)
        #pragma unroll
        for (int nt = 0; nt < 8; ++nt) acc[t][nt] = (f32x4){0.f, 0.f, 0.f, 0.f};

    #pragma unroll
    for (int kc = 0; kc < 4; ++kc) {
        short8 ah[2], al[2];
        #pragma unroll
        for (int t = 0; t < 2; ++t) {
            const float* ap = A + (rowbase + t * 16 + rl) * 128 + kc * 32 + g * 8;
            f32x4 a0 = *(const f32x4*)ap;
            f32x4 a1 = *(const f32x4*)(ap + 4);
            float av[8] = {a0.x, a0.y, a0.z, a0.w, a1.x, a1.y, a1.z, a1.w};
            #pragma unroll
            for (int j = 0; j < 8; ++j) {
                unsigned short hb = bf16_rne(av[j]);
                float hf = __uint_as_float((unsigned)hb << 16);
                ah[t][j] = (short)hb;
                al[t][j] = (short)bf16_rne(av[j] - hf);
            }
        }
        #pragma unroll
        for (int nt = 0; nt < 8; ++nt) {
            int oct = kc * 4 + g, col = nt * 16 + rl;
            short8 bh = *(const short8*)(Bhi + ((size_t)(oct * 128 + col)) * 8);
            short8 bl = *(const short8*)(Blo + ((size_t)(oct * 128 + col)) * 8);
            #pragma unroll
            for (int t = 0; t < 2; ++t) {
                acc[t][nt] = __builtin_amdgcn_mfma_f32_16x16x32_bf16(ah[t], bh, acc[t][nt], 0, 0, 0);
                acc[t][nt] = __builtin_amdgcn_mfma_f32_16x16x32_bf16(ah[t], bl, acc[t][nt], 0, 0, 0);
                acc[t][nt] = __builtin_amdgcn_mfma_f32_16x16x32_bf16(al[t], bh, acc[t][nt], 0, 0, 0);
            }
        }
    }
    #pragma unroll
    for (int nt = 0; nt < 8; ++nt) {
        int col = nt * 16 + rl;
        float bv = bias[col];
        #pragma unroll
        for (int t = 0; t < 2; ++t)
            #pragma unroll
            for (int r = 0; r < 4; ++r) {
                size_t row = rowbase + t * 16 + g * 4 + r;
                C[row * 128 + col] = acc[t][nt][r] + bv;
            }
    }
}

// ---------------- gemm128_heT: gemm128 + LDS-transpose epilogue writing heT bf16 [(n,h)][e][p]
__global__ __launch_bounds__(256) void gemm128_heT(const float* __restrict__ A,
                                                   const unsigned short* __restrict__ Bhi,
                                                   const unsigned short* __restrict__ Blo,
                                                   const float* __restrict__ bias,
                                                   float* __restrict__ C,
                                                   unsigned short* __restrict__ heT) {
    __shared__ __align__(16) unsigned short tbuf[128 * 128];  // swizzled [e][p_local]
    int tid = threadIdx.x, lane = tid & 63, w = tid >> 6;
    size_t rowbase = (size_t)blockIdx.x * 128 + w * 32;
    int rl = lane & 15, g = lane >> 4;
    f32x4 acc[2][8];
    #pragma unroll
    for (int t = 0; t < 2; ++t)
        #pragma unroll
        for (int nt = 0; nt < 8; ++nt) acc[t][nt] = (f32x4){0.f, 0.f, 0.f, 0.f};

    #pragma unroll
    for (int kc = 0; kc < 4; ++kc) {
        short8 ah[2], al[2];
        #pragma unroll
        for (int t = 0; t < 2; ++t) {
            const float* ap = A + (rowbase + t * 16 + rl) * 128 + kc * 32 + g * 8;
            f32x4 a0 = *(const f32x4*)ap;
            f32x4 a1 = *(const f32x4*)(ap + 4);
            float av[8] = {a0.x, a0.y, a0.z, a0.w, a1.x, a1.y, a1.z, a1.w};
            #pragma unroll
            for (int j = 0; j < 8; ++j) {
                unsigned short hb = bf16_rne(av[j]);
                float hf = __uint_as_float((unsigned)hb << 16);
                ah[t][j] = (short)hb;
                al[t][j] = (short)bf16_rne(av[j] - hf);
            }
        }
        #pragma unroll
        for (int nt = 0; nt < 8; ++nt) {
            int oct = kc * 4 + g, col = nt * 16 + rl;
            short8 bh = *(const short8*)(Bhi + ((size_t)(oct * 128 + col)) * 8);
            short8 bl = *(const short8*)(Blo + ((size_t)(oct * 128 + col)) * 8);
            #pragma unroll
            for (int t = 0; t < 2; ++t) {
                acc[t][nt] = __builtin_amdgcn_mfma_f32_16x16x32_bf16(ah[t], bh, acc[t][nt], 0, 0, 0);
                acc[t][nt] = __builtin_amdgcn_mfma_f32_16x16x32_bf16(ah[t], bl, acc[t][nt], 0, 0, 0);
                acc[t][nt] = __builtin_amdgcn_mfma_f32_16x16x32_bf16(al[t], bh, acc[t][nt], 0, 0, 0);
            }
        }
    }
    #pragma unroll
    for (int nt = 0; nt < 8; ++nt) {
        int col = nt * 16 + rl;
        float bv = bias[col];
        #pragma unroll
        for (int t = 0; t < 2; ++t) {
            float v0 = acc[t][nt][0] + bv;
            float v1 = acc[t][nt][1] + bv;
            float v2 = acc[t][nt][2] + bv;
            float v3 = acc[t][nt][3] + bv;
            size_t row = rowbase + t * 16 + g * 4;
            C[row * 128 + col]       = v0;
            C[(row + 1) * 128 + col] = v1;
            C[(row + 2) * 128 + col] = v2;
            C[(row + 3) * 128 + col] = v3;
            int row_loc = w * 32 + t * 16 + g * 4;
            int byte = (col * 256 + row_loc * 2) ^ ((col & 7) << 4);
            *(ushort4*)((char*)tbuf + byte) =
                make_ushort4(bf16_rne(v0), bf16_rne(v1), bf16_rne(v2), bf16_rne(v3));
        }
    }
    __syncthreads();
    int bh2 = blockIdx.x >> 1, p0 = (blockIdx.x & 1) * 128;
    #pragma unroll
    for (int rep = 0; rep < 8; ++rep) {
        int id = rep * 256 + tid;
        int e = id >> 4, j = id & 15;
        int byte = (e * 256 + j * 16) ^ ((e & 7) << 4);
        short8 v = *(const short8*)((char*)tbuf + byte);
        *(short8*)(heT + (size_t)bh2 * 32768 + (size_t)e * 256 + p0 + j * 8) = v;
    }
}

// ---------------- k1b: s = softmax_h(gelu(xh)@W2), eu = exp(a_node - max_h)
__global__ __launch_bounds__(256) void k1b_softmax(const float* __restrict__ xh,
                                                   const float* __restrict__ W2,
                                                   const float* __restrict__ W4,
                                                   float* __restrict__ s_out,
                                                   float* __restrict__ eu) {
    int tid = threadIdx.x, lane = tid & 63, wv = tid >> 6;
    int base = blockIdx.x * 4 + wv;
    int n = base >> 9, l = base & 511;
    int h = lane >> 3, sub = lane & 7;
    const float* xp = xh + (size_t)base * 1024 + h * 128 + sub * 16;
    float xv = 0.f, an = 0.f;
    #pragma unroll
    for (int q = 0; q < 4; ++q) {
        f32x4 v  = *(const f32x4*)(xp + q * 4);
        f32x4 w2 = *(const f32x4*)(W2 + sub * 16 + q * 4);
        f32x4 w4 = *(const f32x4*)(W4 + 128 + sub * 16 + q * 4);
        f32x4 gv = gelu4(v);
        xv += gv.x * w2.x + gv.y * w2.y + gv.z * w2.z + gv.w * w2.w;
        an += gv.x * w4.x + gv.y * w4.y + gv.z * w4.z + gv.w * w4.w;
    }
    xv += __shfl_xor(xv, 1); xv += __shfl_xor(xv, 2); xv += __shfl_xor(xv, 4);
    an += __shfl_xor(an, 1); an += __shfl_xor(an, 2); an += __shfl_xor(an, 4);
    float mx = xv;
    mx = fmaxf(mx, __shfl_xor(mx, 8)); mx = fmaxf(mx, __shfl_xor(mx, 16)); mx = fmaxf(mx, __shfl_xor(mx, 32));
    float ex = expf(xv - mx);
    float sm = ex;
    sm += __shfl_xor(sm, 8); sm += __shfl_xor(sm, 16); sm += __shfl_xor(sm, 32);
    float sv = ex / sm;
    float mxa = an;
    mxa = fmaxf(mxa, __shfl_xor(mxa, 8)); mxa = fmaxf(mxa, __shfl_xor(mxa, 16)); mxa = fmaxf(mxa, __shfl_xor(mxa, 32));
    float euv = expf(an - mxa);
    if (sub == 0) {
        s_out[((size_t)(n * 8 + h)) * 512 + l] = sv;
        eu[(size_t)base * 8 + h] = euv;
    }
}

// ---------------- k2_mfma: heg = gelu(A' @ xh), A'[p,l] = bit(l,p) ? s[l] : 0.125 (bf16, reg-built)
// B via k-packed LDS image: kpk[(l>>3)*128+e][l&7] = bf16(xh[l][e]) -> one ds_read_b128 per fragment.
__global__ __launch_bounds__(512) void k2_mfma(const float* __restrict__ xh,
                                               const float* __restrict__ s_in,
                                               const unsigned* __restrict__ bitsT,
                                               float* __restrict__ heg) {
    __shared__ __align__(16) unsigned short kpk[65536];    // 128 KB
    __shared__ unsigned bT_s[16 * 256];                    // [kt][p], 16 KB
    __shared__ __align__(16) unsigned short smb_s[512];    // bf16(s), 1 KB
    int bh = blockIdx.x;
    int n = bh >> 3, h = bh & 7;
    int tid = threadIdx.x, lane = tid & 63, w = tid >> 6;

    // stage bitsT transposed: bT_s[kt][p]
    #pragma unroll
    for (int i = 0; i < 2; ++i) {
        int id = i * 512 + tid;
        int p = id >> 2, q = id & 3;
        uint4 wds = *(const uint4*)(bitsT + ((size_t)(n * 256 + p)) * 16 + q * 4);
        bT_s[(q * 4 + 0) * 256 + p] = wds.x;
        bT_s[(q * 4 + 1) * 256 + p] = wds.y;
        bT_s[(q * 4 + 2) * 256 + p] = wds.z;
        bT_s[(q * 4 + 3) * 256 + p] = wds.w;
    }
    smb_s[tid] = bf16_rne(s_in[(size_t)bh * 512 + tid]);
    // stage xh -> k-packed bf16 image (coalesced dword loads, conflict-free b128 writes)
    {
        const float* xb = xh + ((size_t)(n * 512) * 8 + h) * 128;
        int e = tid & 127, kgo = tid >> 7;
        #pragma unroll
        for (int rep = 0; rep < 16; ++rep) {
            int kg = rep * 4 + kgo;
            const float* src = xb + (size_t)kg * 8192 + e;
            float v[8];
            #pragma unroll
            for (int j = 0; j < 8; ++j) v[j] = src[j * 1024];
            short8 o;
            #pragma unroll
            for (int j = 0; j < 8; ++j) o[j] = (short)bf16_rne(v[j]);
            *(short8*)&kpk[((kg << 7) + e) * 8] = o;
        }
    }
    __syncthreads();

    int rl = lane & 15, g = lane >> 4;
    int wm = w & 3, wn = w >> 2;        // 4 p-groups x 2 e-groups
    f32x4 acc[4][4];
    #pragma unroll
    for (int mt = 0; mt < 4; ++mt)
        #pragma unroll
        for (int nt = 0; nt < 4; ++nt) acc[mt][nt] = (f32x4){0.f, 0.f, 0.f, 0.f};

    for (int kt = 0; kt < 16; ++kt) {
        short8 sv = *(const short8*)&smb_s[kt * 32 + g * 8];
        short8 bfr[4];
        #pragma unroll
        for (int nt = 0; nt < 4; ++nt)
            bfr[nt] = *(const short8*)&kpk[(((kt * 4 + g) << 7) + wn * 64 + nt * 16 + rl) * 8];
        #pragma unroll
        for (int mt = 0; mt < 4; ++mt) {
            unsigned word = bT_s[kt * 256 + wm * 64 + mt * 16 + rl];
            unsigned byte = (word >> (g * 8)) & 255u;
            short8 af;
            #pragma unroll
            for (int j = 0; j < 8; ++j)
                af[j] = ((byte >> j) & 1u) ? sv[j] : (short)0x3E00;
            #pragma unroll
            for (int nt = 0; nt < 4; ++nt)
                acc[mt][nt] = __builtin_amdgcn_mfma_f32_16x16x32_bf16(af, bfr[nt], acc[mt][nt], 0, 0, 0);
        }
    }

    float* ob = heg + (size_t)bh * (PP * EE);
    #pragma unroll
    for (int mt = 0; mt < 4; ++mt)
        #pragma unroll
        for (int nt = 0; nt < 4; ++nt) {
            int e = (wn * 4 + nt) * 16 + rl;
            #pragma unroll
            for (int r = 0; r < 4; ++r) {
                int p = wm * 64 + mt * 16 + g * 4 + r;
                ob[(size_t)p * 128 + e] = gelu_f(acc[mt][nt][r]);
            }
        }
}

// ---------------- k3b: ev[n,p,h] = exp(gelu(he_row)@W4[:E])
__global__ __launch_bounds__(256) void k3b_ev(const float* __restrict__ he,
                                              const float* __restrict__ W4,
                                              float* __restrict__ ev) {
    int tid = threadIdx.x, lane = tid & 63, wv = tid >> 6;
    size_t R = (size_t)blockIdx.x * 8 + wv * 2 + (lane >> 5);
    int lx = lane & 31;
    f32x4 v = *(const f32x4*)(he + R * 128 + lx * 4);
    f32x4 w = *(const f32x4*)(W4 + lx * 4);
    f32x4 gv = gelu4(v);
    float ae = gv.x * w.x + gv.y * w.y + gv.z * w.z + gv.w * w.w;
    ae += __shfl_xor(ae, 1); ae += __shfl_xor(ae, 2); ae += __shfl_xor(ae, 4);
    ae += __shfl_xor(ae, 8); ae += __shfl_xor(ae, 16);
    if (lx == 0) {
        int n = (int)(R >> 11), h = (int)((R >> 8) & 7), p = (int)(R & 255);
        ev[((size_t)(n * 256 + p)) * 8 + h] = expf(ae);
    }
}

// ---------------- k4_dense: rdm[n][l][p] = bit ? 1/den : 0  (bf16, h-shared)
__global__ __launch_bounds__(256) void k4_dense(const float* __restrict__ eu,
                                                const float* __restrict__ ev,
                                                const unsigned* __restrict__ bits,
                                                unsigned short* __restrict__ rdm) {
    __shared__ float ev_t[256][8];
    int b = blockIdx.x;
    int n = b >> 3, l0 = (b & 7) * 64;
    int tid = threadIdx.x;
    {
        const f32x4* src = (const f32x4*)(ev + (size_t)n * 2048);
        f32x4* dst = (f32x4*)&ev_t[0][0];
        dst[tid] = src[tid];
        dst[tid + 256] = src[tid + 256];
    }
    __syncthreads();
    int l = l0 + (tid >> 2), pq = tid & 3;
    size_t rowg = (size_t)n * 512 + l;
    f32x4 ea = *(const f32x4*)(eu + rowg * 8);
    f32x4 eb = *(const f32x4*)(eu + rowg * 8 + 4);
    unsigned w0 = bits[rowg * 8 + pq * 2], w1 = bits[rowg * 8 + pq * 2 + 1];
    for (int c = 0; c < 8; ++c) {
        short8 o8;
        #pragma unroll
        for (int k = 0; k < 8; ++k) {
            int pl = c * 8 + k;
            int p = pq * 64 + pl;
            f32x4 va = *(const f32x4*)&ev_t[p][0];
            f32x4 vb = *(const f32x4*)&ev_t[p][4];
            float den = ea.x * va.x + ea.y * va.y + ea.z * va.z + ea.w * va.w
                      + eb.x * vb.x + eb.y * vb.y + eb.z * vb.z + eb.w * vb.w;
            unsigned bit = (pl < 32) ? ((w0 >> pl) & 1u) : ((w1 >> (pl - 32)) & 1u);
            float r = bit ? rcp_f(den) : 0.0f;
            o8[k] = (short)bf16_rne(r);
        }
        *(short8*)(rdm + rowg * 256 + pq * 64 + c * 8) = o8;
    }
}

// ---------------- k5_mfma: x_nodes = 0.125*colsum(he) + A @ he ; A[l,p] = bit ? att-0.125 : 0 (bf16)
__global__ __launch_bounds__(512) void k5_mfma(const unsigned short* __restrict__ heT,
                                               const unsigned short* __restrict__ rdm,
                                               const float* __restrict__ eu,
                                               const float* __restrict__ ev,
                                               const unsigned* __restrict__ flags,
                                               const float* __restrict__ x,
                                               float* __restrict__ out) {
    __shared__ __align__(16) unsigned short heT_s[128 * 256];  // swizzled [e][p], 64 KB
    __shared__ __align__(16) unsigned short A_s[64 * 256];     // swizzled [l_loc][p], 32 KB
    __shared__ float evh_s[256];
    __shared__ float euh_s[64];
    __shared__ float cs_s[128];
    __shared__ float csr_s[4][128];
    __shared__ unsigned flg_s[64];

    int bid = blockIdx.x;
    int xcd = bid & 7, slot = bid >> 3;          // group 8 heads of same n per XCD (rdm L2 reuse)
    int n = xcd * 4 + (slot & 3), h = slot >> 2;
    int bh = n * 8 + h;
    int tid = threadIdx.x, lane = tid & 63, w = tid >> 6;

    const unsigned short* hb = heT + (size_t)bh * 32768;
    #pragma unroll
    for (int i = 0; i < 8; ++i) {
        int id = tid + i * 512;
        int e = id >> 5, jj = id & 31;
        short8 v = *(const short8*)(hb + e * 256 + jj * 8);
        *(short8*)((char*)heT_s + ((e * 512 + jj * 16) ^ ((e & 7) << 4))) = v;
    }
    if (tid < 256) evh_s[tid] = ev[((size_t)(n * 256 + tid)) * 8 + h];
    __syncthreads();
    {
        int e = tid & 127, q = tid >> 7;
        float a = 0.f;
        #pragma unroll
        for (int j = 0; j < 8; ++j) {
            int byte = (e * 512 + (q * 64 + j * 8) * 2) ^ ((e & 7) << 4);
            short8 v = *(const short8*)((char*)heT_s + byte);
            #pragma unroll
            for (int k = 0; k < 8; ++k) a += bf2f(v[k]);
        }
        csr_s[q][e] = a;
    }
    __syncthreads();
    if (tid < 128) cs_s[tid] = 0.125f * (csr_s[0][tid] + csr_s[1][tid] + csr_s[2][tid] + csr_s[3][tid]);

    int rl = lane & 15, g = lane >> 4;
    int wm = w & 1, wn = w >> 1;
    int swz = (rl & 7) << 4;

    for (int lt = 0; lt < 8; ++lt) {
        int l0 = lt * 64;
        if (tid < 64) {
            euh_s[tid] = eu[((size_t)(n * 512 + l0 + tid)) * 8 + h];
            flg_s[tid] = flags[n * 512 + l0 + tid];
        }
        __syncthreads();
        {
            int l_loc = tid >> 3, p0 = (tid & 7) * 32;
            float euh = euh_s[l_loc];
            const unsigned short* rp = rdm + ((size_t)(n * 512 + l0 + l_loc)) * 256 + p0;
            #pragma unroll
            for (int c = 0; c < 4; ++c) {
                short8 rv = *(const short8*)(rp + c * 8);
                short8 o8;
                #pragma unroll
                for (int k = 0; k < 8; ++k) {
                    unsigned u = (unsigned)(unsigned short)rv[k];
                    float rf = __uint_as_float(u << 16);
                    float m125 = (u != 0u) ? -0.125f : 0.0f;
                    float a = fmaf(euh * evh_s[p0 + c * 8 + k], rf, m125);
                    o8[k] = (short)bf16_rne(a);
                }
                *(short8*)((char*)A_s + ((l_loc * 512 + (p0 + c * 8) * 2) ^ ((l_loc & 7) << 4))) = o8;
            }
        }
        __syncthreads();
        f32x4 acc[2][2];
        #pragma unroll
        for (int i = 0; i < 2; ++i)
            #pragma unroll
            for (int j = 0; j < 2; ++j) acc[i][j] = (f32x4){0.f, 0.f, 0.f, 0.f};
        #pragma unroll
        for (int kt = 0; kt < 8; ++kt) {
            short8 af[2], bfr[2];
            #pragma unroll
            for (int i = 0; i < 2; ++i) {
                int arow = (wm * 2 + i) * 16 + rl;
                af[i] = *(const short8*)((char*)A_s + ((arow * 512 + kt * 64 + g * 16) ^ swz));
                int e = (wn * 2 + i) * 16 + rl;
                bfr[i] = *(const short8*)((char*)heT_s + ((e * 512 + kt * 64 + g * 16) ^ swz));
            }
            acc[0][0] = __builtin_amdgcn_mfma_f32_16x16x32_bf16(af[0], bfr[0], acc[0][0], 0, 0, 0);
            acc[0][1] = __builtin_amdgcn_mfma_f32_16x16x32_bf16(af[0], bfr[1], acc[0][1], 0, 0, 0);
            acc[1][0] = __builtin_amdgcn_mfma_f32_16x16x32_bf16(af[1], bfr[0], acc[1][0], 0, 0, 0);
            acc[1][1] = __builtin_amdgcn_mfma_f32_16x16x32_bf16(af[1], bfr[1], acc[1][1], 0, 0, 0);
        }
        #pragma unroll
        for (int i = 0; i < 2; ++i) {
            #pragma unroll
            for (int j = 0; j < 2; ++j) {
                int e = (wn * 2 + j) * 16 + rl;
                float csv = cs_s[e];
                #pragma unroll
                for (int r = 0; r < 4; ++r) {
                    int row = (wm * 2 + i) * 16 + g * 4 + r;
                    int l = l0 + row;
                    size_t addr = ((size_t)(n * 512 + l)) * 1024 + h * 128 + e;
                    if (flg_s[row]) {
                        out[addr] = x[addr];
                    } else {
                        out[addr] = gelu_f(acc[i][j][r] + csv);
                    }
                }
            }
        }
        __syncthreads();
    }
}

extern "C" void kernel_launch(void* const* d_in, const int* in_sizes, int n_in,
                              void* d_out, int out_size, void* d_ws, size_t ws_size,
                              hipStream_t stream) {
    (void)in_sizes; (void)n_in; (void)out_size; (void)ws_size;
    const float* x   = (const float*)d_in[0];
    const float* adj = (const float*)d_in[1];
    const float* W1  = (const float*)d_in[2];
    const float* b1  = (const float*)d_in[3];
    const float* W2  = (const float*)d_in[4];
    const float* W3  = (const float*)d_in[6];
    const float* b3  = (const float*)d_in[7];
    const float* W4  = (const float*)d_in[8];
    float* out = (float*)d_out;

    char* ws = (char*)d_ws;
    size_t off = 0;
    auto alloc = [&](size_t bytes) -> void* {
        void* p = ws + off;
        off += (bytes + 255) & ~(size_t)255;
        return p;
    };
    float* xh   = (float*)alloc((size_t)NB * LL * HH * EE * 4);        // 67 MB  [(n,l,h)][e]
    float* s    = (float*)alloc((size_t)NB * HH * LL * 4);
    float* eu   = (float*)alloc((size_t)NB * LL * HH * 4);
    float* ev   = (float*)alloc((size_t)NB * PP * HH * 4);
    float* heg  = (float*)alloc((size_t)NB * HH * PP * EE * 4);        // 33.5 MB [(n,h,p)][e]
    float* he   = (float*)alloc((size_t)NB * HH * PP * EE * 4);        // 33.5 MB
    unsigned short* heT = (unsigned short*)alloc((size_t)NB * HH * EE * PP * 2);  // 16.8 MB [(n,h)][e][p]
    unsigned short* rdm = (unsigned short*)alloc((size_t)NB * LL * PP * 2);       // 8.4 MB [n][l][p]
    unsigned* bits  = (unsigned*)alloc((size_t)NB * LL * 8 * 4);
    unsigned* bitsT = (unsigned*)alloc((size_t)NB * PP * 16 * 4);
    unsigned* flags = (unsigned*)alloc((size_t)NB * LL * 4);
    unsigned short* W1h = (unsigned short*)alloc(16384 * 2);
    unsigned short* W1l = (unsigned short*)alloc(16384 * 2);
    unsigned short* W3h = (unsigned short*)alloc(16384 * 2);
    unsigned short* W3l = (unsigned short*)alloc(16384 * 2);

    hipLaunchKernelGGL(kpack, dim3(2), dim3(256), 0, stream, W1, W3, W1h, W1l, W3h, W3l);
    hipLaunchKernelGGL(k0_bits, dim3(NB * 8), dim3(256), 0, stream, adj, bits, bitsT, flags);
    hipLaunchKernelGGL(gemm128, dim3(1024), dim3(256), 0, stream, x, W1h, W1l, b1, xh);
    hipLaunchKernelGGL(k1b_softmax, dim3(4096), dim3(256), 0, stream, xh, W2, W4, s, eu);
    hipLaunchKernelGGL(k2_mfma, dim3(NB * HH), dim3(512), 0, stream, xh, s, bitsT, heg);
    hipLaunchKernelGGL(gemm128_heT, dim3(512), dim3(256), 0, stream, heg, W3h, W3l, b3, he, heT);
    hipLaunchKernelGGL(k3b_ev, dim3(8192), dim3(256), 0, stream, he, W4, ev);
    hipLaunchKernelGGL(k4_dense, dim3(NB * 8), dim3(256), 0, stream, eu, ev, bits, rdm);
    hipLaunchKernelGGL(k5_mfma, dim3(NB * HH), dim3(512), 0, stream, heT, rdm, eu, ev, flags, x, out);
}

// Round 7
// 230.398 us; speedup vs baseline: 2.8009x; 1.0741x over previous
//
#include <hip/hip_runtime.h>
#include <math.h>

#define NB 32
#define LL 512
#define PP 256
#define HH 8
#define EE 128
#define DD 1024

typedef __attribute__((ext_vector_type(4))) float f32x4;
typedef __attribute__((ext_vector_type(8))) short short8;

__device__ __forceinline__ float gelu_f(float v) {
    return 0.5f * v * (1.0f + erff(v * 0.70710678118654752f));
}
__device__ __forceinline__ float rcp_f(float v) {
    float r; asm("v_rcp_f32 %0, %1" : "=v"(r) : "v"(v)); return r;
}
__device__ __forceinline__ unsigned short bf16_rne(float v) {
    unsigned u = __float_as_uint(v);
    unsigned r = u + 0x7FFFu + ((u >> 16) & 1u);
    return (unsigned short)(r >> 16);
}
__device__ __forceinline__ float bf2f(short s) {
    return __uint_as_float(((unsigned)(unsigned short)s) << 16);
}
__device__ __forceinline__ f32x4 gelu4(f32x4 v) {
    f32x4 g; g.x = gelu_f(v.x); g.y = gelu_f(v.y); g.z = gelu_f(v.z); g.w = gelu_f(v.w); return g;
}

// ---------------- kpack: W (128x128 fp32) -> bf16 hi/lo in MFMA B-fragment order
__global__ __launch_bounds__(256) void kpack(const float* __restrict__ W1,
                                             const float* __restrict__ W3,
                                             unsigned short* __restrict__ W1h,
                                             unsigned short* __restrict__ W1l,
                                             unsigned short* __restrict__ W3h,
                                             unsigned short* __restrict__ W3l) {
    const float* W = blockIdx.x ? W3 : W1;
    unsigned short* Ph = blockIdx.x ? W3h : W1h;
    unsigned short* Pl = blockIdx.x ? W3l : W1l;
    for (int i = threadIdx.x; i < 16384; i += 256) {
        int oct = i >> 10, col = (i >> 3) & 127, j = i & 7;
        float v = W[(oct * 8 + j) * 128 + col];
        unsigned short hb = bf16_rne(v);
        float hf = __uint_as_float((unsigned)hb << 16);
        Ph[i] = hb;
        Pl[i] = bf16_rne(v - hf);
    }
}

// ---------------- K0: pack mask to bits (row-major + col-major) + no-edge flags
__global__ __launch_bounds__(256) void k0_bits(const float* __restrict__ adj,
                                               unsigned* __restrict__ bits,
                                               unsigned* __restrict__ bitsT,
                                               unsigned* __restrict__ flags) {
    __shared__ unsigned lbits[64][8];
    int n  = blockIdx.x >> 3;
    int l0 = (blockIdx.x & 7) * 64;
    int lane = threadIdx.x & 63;
    int wv   = threadIdx.x >> 6;
    for (int r = wv; r < 64; r += 4) {
        int l = l0 + r;
        const float* row = adj + ((size_t)n * LL + l) * PP;
        int cnt = 0;
        for (int c = 0; c < 4; ++c) {
            float v = row[c * 64 + lane];
            unsigned long long b = __ballot(v != 0.0f);
            if (lane == 0) {
                lbits[r][c * 2]     = (unsigned)b;
                lbits[r][c * 2 + 1] = (unsigned)(b >> 32);
                cnt += __popcll(b);
            }
        }
        if (lane == 0) {
            flags[n * LL + l] = (cnt == 0) ? 1u : 0u;
            for (int w = 0; w < 8; ++w)
                bits[((size_t)n * LL + l) * 8 + w] = lbits[r][w];
        }
    }
    __syncthreads();
    int p = threadIdx.x;
    unsigned w0 = 0, w1 = 0;
    int wp = p >> 5, bp = p & 31;
    for (int j = 0; j < 32; ++j) {
        w0 |= ((lbits[j][wp] >> bp) & 1u) << j;
        w1 |= ((lbits[j + 32][wp] >> bp) & 1u) << j;
    }
    bitsT[((size_t)n * PP + p) * 16 + (l0 >> 5)]     = w0;
    bitsT[((size_t)n * PP + p) * 16 + (l0 >> 5) + 1] = w1;
}

// ---------------- gemm128: C[M x 128] = A[M x 128] @ W[128 x 128] + bias (3-pass split bf16)
__global__ __launch_bounds__(256) void gemm128(const float* __restrict__ A,
                                               const unsigned short* __restrict__ Bhi,
                                               const unsigned short* __restrict__ Blo,
                                               const float* __restrict__ bias,
                                               float* __restrict__ C) {
    int tid = threadIdx.x, lane = tid & 63, w = tid >> 6;
    size_t rowbase = (size_t)blockIdx.x * 128 + w * 32;
    int rl = lane & 15, g = lane >> 4;
    f32x4 acc[2][8];
    #pragma unroll
    for (int t = 0; t < 2; ++t)
        #pragma unroll
        for (int nt = 0; nt < 8; ++nt) acc[t][nt] = (f32x4){0.f, 0.f, 0.f, 0.f};

    #pragma unroll
    for (int kc = 0; kc < 4; ++kc) {
        short8 ah[2], al[2];
        #pragma unroll
        for (int t = 0; t < 2; ++t) {
            const float* ap = A + (rowbase + t * 16 + rl) * 128 + kc * 32 + g * 8;
            f32x4 a0 = *(const f32x4*)ap;
            f32x4 a1 = *(const f32x4*)(ap + 4);
            float av[8] = {a0.x, a0.y, a0.z, a0.w, a1.x, a1.y, a1.z, a1.w};
            #pragma unroll
            for (int j = 0; j < 8; ++j) {
                unsigned short hb = bf16_rne(av[j]);
                float hf = __uint_as_float((unsigned)hb << 16);
                ah[t][j] = (short)hb;
                al[t][j] = (short)bf16_rne(av[j] - hf);
            }
        }
        #pragma unroll
        for (int nt = 0; nt < 8; ++nt) {
            int oct = kc * 4 + g, col = nt * 16 + rl;
            short8 bh = *(const short8*)(Bhi + ((size_t)(oct * 128 + col)) * 8);
            short8 bl = *(const short8*)(Blo + ((size_t)(oct * 128 + col)) * 8);
            #pragma unroll
            for (int t = 0; t < 2; ++t) {
                acc[t][nt] = __builtin_amdgcn_mfma_f32_16x16x32_bf16(ah[t], bh, acc[t][nt], 0, 0, 0);
                acc[t][nt] = __builtin_amdgcn_mfma_f32_16x16x32_bf16(ah[t], bl, acc[t][nt], 0, 0, 0);
                acc[t][nt] = __builtin_amdgcn_mfma_f32_16x16x32_bf16(al[t], bh, acc[t][nt], 0, 0, 0);
            }
        }
    }
    #pragma unroll
    for (int nt = 0; nt < 8; ++nt) {
        int col = nt * 16 + rl;
        float bv = bias[col];
        #pragma unroll
        for (int t = 0; t < 2; ++t)
            #pragma unroll
            for (int r = 0; r < 4; ++r) {
                size_t row = rowbase + t * 16 + g * 4 + r;
                C[row * 128 + col] = acc[t][nt][r] + bv;
            }
    }
}

// ---------------- gemm128_heT: gemm128 + LDS-transpose epilogue writing heT bf16 [(n,h)][e][p]
__global__ __launch_bounds__(256) void gemm128_heT(const float* __restrict__ A,
                                                   const unsigned short* __restrict__ Bhi,
                                                   const unsigned short* __restrict__ Blo,
                                                   const float* __restrict__ bias,
                                                   float* __restrict__ C,
                                                   unsigned short* __restrict__ heT) {
    __shared__ __align__(16) unsigned short tbuf[128 * 128];  // swizzled [e][p_local]
    int tid = threadIdx.x, lane = tid & 63, w = tid >> 6;
    size_t rowbase = (size_t)blockIdx.x * 128 + w * 32;
    int rl = lane & 15, g = lane >> 4;
    f32x4 acc[2][8];
    #pragma unroll
    for (int t = 0; t < 2; ++t)
        #pragma unroll
        for (int nt = 0; nt < 8; ++nt) acc[t][nt] = (f32x4){0.f, 0.f, 0.f, 0.f};

    #pragma unroll
    for (int kc = 0; kc < 4; ++kc) {
        short8 ah[2], al[2];
        #pragma unroll
        for (int t = 0; t < 2; ++t) {
            const float* ap = A + (rowbase + t * 16 + rl) * 128 + kc * 32 + g * 8;
            f32x4 a0 = *(const f32x4*)ap;
            f32x4 a1 = *(const f32x4*)(ap + 4);
            float av[8] = {a0.x, a0.y, a0.z, a0.w, a1.x, a1.y, a1.z, a1.w};
            #pragma unroll
            for (int j = 0; j < 8; ++j) {
                unsigned short hb = bf16_rne(av[j]);
                float hf = __uint_as_float((unsigned)hb << 16);
                ah[t][j] = (short)hb;
                al[t][j] = (short)bf16_rne(av[j] - hf);
            }
        }
        #pragma unroll
        for (int nt = 0; nt < 8; ++nt) {
            int oct = kc * 4 + g, col = nt * 16 + rl;
            short8 bh = *(const short8*)(Bhi + ((size_t)(oct * 128 + col)) * 8);
            short8 bl = *(const short8*)(Blo + ((size_t)(oct * 128 + col)) * 8);
            #pragma unroll
            for (int t = 0; t < 2; ++t) {
                acc[t][nt] = __builtin_amdgcn_mfma_f32_16x16x32_bf16(ah[t], bh, acc[t][nt], 0, 0, 0);
                acc[t][nt] = __builtin_amdgcn_mfma_f32_16x16x32_bf16(ah[t], bl, acc[t][nt], 0, 0, 0);
                acc[t][nt] = __builtin_amdgcn_mfma_f32_16x16x32_bf16(al[t], bh, acc[t][nt], 0, 0, 0);
            }
        }
    }
    #pragma unroll
    for (int nt = 0; nt < 8; ++nt) {
        int col = nt * 16 + rl;
        float bv = bias[col];
        #pragma unroll
        for (int t = 0; t < 2; ++t) {
            float v0 = acc[t][nt][0] + bv;
            float v1 = acc[t][nt][1] + bv;
            float v2 = acc[t][nt][2] + bv;
            float v3 = acc[t][nt][3] + bv;
            size_t row = rowbase + t * 16 + g * 4;
            C[row * 128 + col]       = v0;
            C[(row + 1) * 128 + col] = v1;
            C[(row + 2) * 128 + col] = v2;
            C[(row + 3) * 128 + col] = v3;
            int row_loc = w * 32 + t * 16 + g * 4;
            int byte = (col * 256 + row_loc * 2) ^ ((col & 7) << 4);
            *(ushort4*)((char*)tbuf + byte) =
                make_ushort4(bf16_rne(v0), bf16_rne(v1), bf16_rne(v2), bf16_rne(v3));
        }
    }
    __syncthreads();
    int bh2 = blockIdx.x >> 1, p0 = (blockIdx.x & 1) * 128;
    #pragma unroll
    for (int rep = 0; rep < 8; ++rep) {
        int id = rep * 256 + tid;
        int e = id >> 4, j = id & 15;
        int byte = (e * 256 + j * 16) ^ ((e & 7) << 4);
        short8 v = *(const short8*)((char*)tbuf + byte);
        *(short8*)(heT + (size_t)bh2 * 32768 + (size_t)e * 256 + p0 + j * 8) = v;
    }
}

// ---------------- k1b: s = softmax_h(gelu(xh)@W2), eu = exp(a_node - max_h)
__global__ __launch_bounds__(256) void k1b_softmax(const float* __restrict__ xh,
                                                   const float* __restrict__ W2,
                                                   const float* __restrict__ W4,
                                                   float* __restrict__ s_out,
                                                   float* __restrict__ eu) {
    int tid = threadIdx.x, lane = tid & 63, wv = tid >> 6;
    int base = blockIdx.x * 4 + wv;
    int n = base >> 9, l = base & 511;
    int h = lane >> 3, sub = lane & 7;
    const float* xp = xh + (size_t)base * 1024 + h * 128 + sub * 16;
    float xv = 0.f, an = 0.f;
    #pragma unroll
    for (int q = 0; q < 4; ++q) {
        f32x4 v  = *(const f32x4*)(xp + q * 4);
        f32x4 w2 = *(const f32x4*)(W2 + sub * 16 + q * 4);
        f32x4 w4 = *(const f32x4*)(W4 + 128 + sub * 16 + q * 4);
        f32x4 gv = gelu4(v);
        xv += gv.x * w2.x + gv.y * w2.y + gv.z * w2.z + gv.w * w2.w;
        an += gv.x * w4.x + gv.y * w4.y + gv.z * w4.z + gv.w * w4.w;
    }
    xv += __shfl_xor(xv, 1); xv += __shfl_xor(xv, 2); xv += __shfl_xor(xv, 4);
    an += __shfl_xor(an, 1); an += __shfl_xor(an, 2); an += __shfl_xor(an, 4);
    float mx = xv;
    mx = fmaxf(mx, __shfl_xor(mx, 8)); mx = fmaxf(mx, __shfl_xor(mx, 16)); mx = fmaxf(mx, __shfl_xor(mx, 32));
    float ex = expf(xv - mx);
    float sm = ex;
    sm += __shfl_xor(sm, 8); sm += __shfl_xor(sm, 16); sm += __shfl_xor(sm, 32);
    float sv = ex / sm;
    float mxa = an;
    mxa = fmaxf(mxa, __shfl_xor(mxa, 8)); mxa = fmaxf(mxa, __shfl_xor(mxa, 16)); mxa = fmaxf(mxa, __shfl_xor(mxa, 32));
    float euv = expf(an - mxa);
    if (sub == 0) {
        s_out[((size_t)(n * 8 + h)) * 512 + l] = sv;
        eu[(size_t)base * 8 + h] = euv;
    }
}

// ---------------- k2_mfma: heg = gelu(A' @ xh); 1024 threads (16 waves) for occupancy
__global__ __launch_bounds__(1024) void k2_mfma(const float* __restrict__ xh,
                                                const float* __restrict__ s_in,
                                                const unsigned* __restrict__ bitsT,
                                                float* __restrict__ heg) {
    __shared__ __align__(16) unsigned short kpk[65536];    // 128 KB
    __shared__ unsigned bT_s[16 * 256];                    // [kt][p], 16 KB
    __shared__ __align__(16) unsigned short smb_s[512];    // bf16(s), 1 KB
    int bh = blockIdx.x;
    int n = bh >> 3, h = bh & 7;
    int tid = threadIdx.x, lane = tid & 63, w = tid >> 6;

    // stage bitsT transposed: bT_s[kt][p]
    {
        int p = tid >> 2, q = tid & 3;
        uint4 wds = *(const uint4*)(bitsT + ((size_t)(n * 256 + p)) * 16 + q * 4);
        bT_s[(q * 4 + 0) * 256 + p] = wds.x;
        bT_s[(q * 4 + 1) * 256 + p] = wds.y;
        bT_s[(q * 4 + 2) * 256 + p] = wds.z;
        bT_s[(q * 4 + 3) * 256 + p] = wds.w;
    }
    if (tid < 512) smb_s[tid] = bf16_rne(s_in[(size_t)bh * 512 + tid]);
    // stage xh -> k-packed bf16 image (coalesced dword loads, conflict-free b128 writes)
    {
        const float* xb = xh + ((size_t)(n * 512) * 8 + h) * 128;
        int e = tid & 127, kgo = tid >> 7;   // kgo 0..7
        #pragma unroll
        for (int rep = 0; rep < 8; ++rep) {
            int kg = rep * 8 + kgo;
            const float* src = xb + (size_t)kg * 8192 + e;
            float v[8];
            #pragma unroll
            for (int j = 0; j < 8; ++j) v[j] = src[j * 1024];
            short8 o;
            #pragma unroll
            for (int j = 0; j < 8; ++j) o[j] = (short)bf16_rne(v[j]);
            *(short8*)&kpk[((kg << 7) + e) * 8] = o;
        }
    }
    __syncthreads();

    int rl = lane & 15, g = lane >> 4;
    int wm = w & 7, wn = w >> 3;        // 8 p-groups (2 mt each) x 2 e-halves (4 nt each)
    f32x4 acc[2][4];
    #pragma unroll
    for (int i = 0; i < 2; ++i)
        #pragma unroll
        for (int nt = 0; nt < 4; ++nt) acc[i][nt] = (f32x4){0.f, 0.f, 0.f, 0.f};

    for (int kt = 0; kt < 16; ++kt) {
        short8 sv = *(const short8*)&smb_s[kt * 32 + g * 8];
        short8 bfr[4];
        #pragma unroll
        for (int nt = 0; nt < 4; ++nt)
            bfr[nt] = *(const short8*)&kpk[(((kt * 4 + g) << 7) + wn * 64 + nt * 16 + rl) * 8];
        #pragma unroll
        for (int i = 0; i < 2; ++i) {
            unsigned word = bT_s[kt * 256 + (wm * 2 + i) * 16 + rl];
            unsigned byte = (word >> (g * 8)) & 255u;
            short8 af;
            #pragma unroll
            for (int j = 0; j < 8; ++j)
                af[j] = ((byte >> j) & 1u) ? sv[j] : (short)0x3E00;
            #pragma unroll
            for (int nt = 0; nt < 4; ++nt)
                acc[i][nt] = __builtin_amdgcn_mfma_f32_16x16x32_bf16(af, bfr[nt], acc[i][nt], 0, 0, 0);
        }
    }

    float* ob = heg + (size_t)bh * (PP * EE);
    #pragma unroll
    for (int i = 0; i < 2; ++i)
        #pragma unroll
        for (int nt = 0; nt < 4; ++nt) {
            int e = wn * 64 + nt * 16 + rl;
            #pragma unroll
            for (int r = 0; r < 4; ++r) {
                int p = (wm * 2 + i) * 16 + g * 4 + r;
                ob[(size_t)p * 128 + e] = gelu_f(acc[i][nt][r]);
            }
        }
}

// ---------------- k3b: ev[n,p,h] = exp(gelu(he_row)@W4[:E])
__global__ __launch_bounds__(256) void k3b_ev(const float* __restrict__ he,
                                              const float* __restrict__ W4,
                                              float* __restrict__ ev) {
    int tid = threadIdx.x, lane = tid & 63, wv = tid >> 6;
    size_t R = (size_t)blockIdx.x * 8 + wv * 2 + (lane >> 5);
    int lx = lane & 31;
    f32x4 v = *(const f32x4*)(he + R * 128 + lx * 4);
    f32x4 w = *(const f32x4*)(W4 + lx * 4);
    f32x4 gv = gelu4(v);
    float ae = gv.x * w.x + gv.y * w.y + gv.z * w.z + gv.w * w.w;
    ae += __shfl_xor(ae, 1); ae += __shfl_xor(ae, 2); ae += __shfl_xor(ae, 4);
    ae += __shfl_xor(ae, 8); ae += __shfl_xor(ae, 16);
    if (lx == 0) {
        int n = (int)(R >> 11), h = (int)((R >> 8) & 7), p = (int)(R & 255);
        ev[((size_t)(n * 256 + p)) * 8 + h] = expf(ae);
    }
}

// ---------------- k4_dense: rdm[n][l][p] = bit ? 1/den : 0  (bf16, h-shared)
__global__ __launch_bounds__(256) void k4_dense(const float* __restrict__ eu,
                                                const float* __restrict__ ev,
                                                const unsigned* __restrict__ bits,
                                                unsigned short* __restrict__ rdm) {
    __shared__ float ev_t[256][8];
    int b = blockIdx.x;
    int n = b >> 3, l0 = (b & 7) * 64;
    int tid = threadIdx.x;
    {
        const f32x4* src = (const f32x4*)(ev + (size_t)n * 2048);
        f32x4* dst = (f32x4*)&ev_t[0][0];
        dst[tid] = src[tid];
        dst[tid + 256] = src[tid + 256];
    }
    __syncthreads();
    int l = l0 + (tid >> 2), pq = tid & 3;
    size_t rowg = (size_t)n * 512 + l;
    f32x4 ea = *(const f32x4*)(eu + rowg * 8);
    f32x4 eb = *(const f32x4*)(eu + rowg * 8 + 4);
    unsigned w0 = bits[rowg * 8 + pq * 2], w1 = bits[rowg * 8 + pq * 2 + 1];
    for (int c = 0; c < 8; ++c) {
        short8 o8;
        #pragma unroll
        for (int k = 0; k < 8; ++k) {
            int pl = c * 8 + k;
            int p = pq * 64 + pl;
            f32x4 va = *(const f32x4*)&ev_t[p][0];
            f32x4 vb = *(const f32x4*)&ev_t[p][4];
            float den = ea.x * va.x + ea.y * va.y + ea.z * va.z + ea.w * va.w
                      + eb.x * vb.x + eb.y * vb.y + eb.z * vb.z + eb.w * vb.w;
            unsigned bit = (pl < 32) ? ((w0 >> pl) & 1u) : ((w1 >> (pl - 32)) & 1u);
            float r = bit ? rcp_f(den) : 0.0f;
            o8[k] = (short)bf16_rne(r);
        }
        *(short8*)(rdm + rowg * 256 + pq * 64 + c * 8) = o8;
    }
}

// ---------------- k5_mfma: x_nodes = 0.125*colsum(he) + A @ he; 1024 threads (16 waves)
__global__ __launch_bounds__(1024) void k5_mfma(const unsigned short* __restrict__ heT,
                                                const unsigned short* __restrict__ rdm,
                                                const float* __restrict__ eu,
                                                const float* __restrict__ ev,
                                                const unsigned* __restrict__ flags,
                                                const float* __restrict__ x,
                                                float* __restrict__ out) {
    __shared__ __align__(16) unsigned short heT_s[128 * 256];  // swizzled [e][p], 64 KB
    __shared__ __align__(16) unsigned short A_s[64 * 256];     // swizzled [l_loc][p], 32 KB
    __shared__ float evh_s[256];
    __shared__ float euh_s[64];
    __shared__ float cs_s[128];
    __shared__ float csr_s[4][128];
    __shared__ unsigned flg_s[64];

    int bid = blockIdx.x;
    int xcd = bid & 7, slot = bid >> 3;          // group 8 heads of same n per XCD (rdm L2 reuse)
    int n = xcd * 4 + (slot & 3), h = slot >> 2;
    int bh = n * 8 + h;
    int tid = threadIdx.x, lane = tid & 63, w = tid >> 6;

    const unsigned short* hb = heT + (size_t)bh * 32768;
    #pragma unroll
    for (int i = 0; i < 4; ++i) {
        int id = tid + i * 1024;
        int e = id >> 5, jj = id & 31;
        short8 v = *(const short8*)(hb + e * 256 + jj * 8);
        *(short8*)((char*)heT_s + ((e * 512 + jj * 16) ^ ((e & 7) << 4))) = v;
    }
    if (tid < 256) evh_s[tid] = ev[((size_t)(n * 256 + tid)) * 8 + h];
    __syncthreads();
    if (tid < 512) {
        int e = tid & 127, q = tid >> 7;
        float a = 0.f;
        #pragma unroll
        for (int j = 0; j < 8; ++j) {
            int byte = (e * 512 + (q * 64 + j * 8) * 2) ^ ((e & 7) << 4);
            short8 v = *(const short8*)((char*)heT_s + byte);
            #pragma unroll
            for (int k = 0; k < 8; ++k) a += bf2f(v[k]);
        }
        csr_s[q][e] = a;
    }
    __syncthreads();
    if (tid < 128) cs_s[tid] = 0.125f * (csr_s[0][tid] + csr_s[1][tid] + csr_s[2][tid] + csr_s[3][tid]);

    int rl = lane & 15, g = lane >> 4;
    int wm = w & 3, wn = w >> 2;       // 4 mt x 4 e-groups (2 nt each)
    int swz = (rl & 7) << 4;

    for (int lt = 0; lt < 8; ++lt) {
        int l0 = lt * 64;
        if (tid < 64) {
            euh_s[tid] = eu[((size_t)(n * 512 + l0 + tid)) * 8 + h];
            flg_s[tid] = flags[n * 512 + l0 + tid];
        }
        __syncthreads();
        {
            int l_loc = tid >> 4, p8 = (tid & 15) * 16;
            float euh = euh_s[l_loc];
            const unsigned short* rp = rdm + ((size_t)(n * 512 + l0 + l_loc)) * 256 + p8;
            #pragma unroll
            for (int c = 0; c < 2; ++c) {
                short8 rv = *(const short8*)(rp + c * 8);
                short8 o8;
                #pragma unroll
                for (int k = 0; k < 8; ++k) {
                    unsigned u = (unsigned)(unsigned short)rv[k];
                    float rf = __uint_as_float(u << 16);
                    float m125 = (u != 0u) ? -0.125f : 0.0f;
                    float a = fmaf(euh * evh_s[p8 + c * 8 + k], rf, m125);
                    o8[k] = (short)bf16_rne(a);
                }
                *(short8*)((char*)A_s + ((l_loc * 512 + (p8 + c * 8) * 2) ^ ((l_loc & 7) << 4))) = o8;
            }
        }
        __syncthreads();
        f32x4 acc[2];
        acc[0] = (f32x4){0.f, 0.f, 0.f, 0.f};
        acc[1] = (f32x4){0.f, 0.f, 0.f, 0.f};
        #pragma unroll
        for (int kt = 0; kt < 8; ++kt) {
            int arow = wm * 16 + rl;
            short8 af = *(const short8*)((char*)A_s + ((arow * 512 + kt * 64 + g * 16) ^ swz));
            short8 b0, b1;
            {
                int e0 = wn * 32 + rl;
                int e1 = wn * 32 + 16 + rl;
                b0 = *(const short8*)((char*)heT_s + ((e0 * 512 + kt * 64 + g * 16) ^ swz));
                b1 = *(const short8*)((char*)heT_s + ((e1 * 512 + kt * 64 + g * 16) ^ swz));
            }
            acc[0] = __builtin_amdgcn_mfma_f32_16x16x32_bf16(af, b0, acc[0], 0, 0, 0);
            acc[1] = __builtin_amdgcn_mfma_f32_16x16x32_bf16(af, b1, acc[1], 0, 0, 0);
        }
        #pragma unroll
        for (int j = 0; j < 2; ++j) {
            int e = wn * 32 + j * 16 + rl;
            float csv = cs_s[e];
            #pragma unroll
            for (int r = 0; r < 4; ++r) {
                int row = wm * 16 + g * 4 + r;
                int l = l0 + row;
                size_t addr = ((size_t)(n * 512 + l)) * 1024 + h * 128 + e;
                if (flg_s[row]) {
                    out[addr] = x[addr];
                } else {
                    out[addr] = gelu_f(acc[j][r] + csv);
                }
            }
        }
        __syncthreads();
    }
}

extern "C" void kernel_launch(void* const* d_in, const int* in_sizes, int n_in,
                              void* d_out, int out_size, void* d_ws, size_t ws_size,
                              hipStream_t stream) {
    (void)in_sizes; (void)n_in; (void)out_size; (void)ws_size;
    const float* x   = (const float*)d_in[0];
    const float* adj = (const float*)d_in[1];
    const float* W1  = (const float*)d_in[2];
    const float* b1  = (const float*)d_in[3];
    const float* W2  = (const float*)d_in[4];
    const float* W3  = (const float*)d_in[6];
    const float* b3  = (const float*)d_in[7];
    const float* W4  = (const float*)d_in[8];
    float* out = (float*)d_out;

    char* ws = (char*)d_ws;
    size_t off = 0;
    auto alloc = [&](size_t bytes) -> void* {
        void* p = ws + off;
        off += (bytes + 255) & ~(size_t)255;
        return p;
    };
    float* xh   = (float*)alloc((size_t)NB * LL * HH * EE * 4);        // 67 MB  [(n,l,h)][e]
    float* s    = (float*)alloc((size_t)NB * HH * LL * 4);
    float* eu   = (float*)alloc((size_t)NB * LL * HH * 4);
    float* ev   = (float*)alloc((size_t)NB * PP * HH * 4);
    float* heg  = (float*)alloc((size_t)NB * HH * PP * EE * 4);        // 33.5 MB [(n,h,p)][e]
    float* he   = (float*)alloc((size_t)NB * HH * PP * EE * 4);        // 33.5 MB
    unsigned short* heT = (unsigned short*)alloc((size_t)NB * HH * EE * PP * 2);  // 16.8 MB [(n,h)][e][p]
    unsigned short* rdm = (unsigned short*)alloc((size_t)NB * LL * PP * 2);       // 8.4 MB [n][l][p]
    unsigned* bits  = (unsigned*)alloc((size_t)NB * LL * 8 * 4);
    unsigned* bitsT = (unsigned*)alloc((size_t)NB * PP * 16 * 4);
    unsigned* flags = (unsigned*)alloc((size_t)NB * LL * 4);
    unsigned short* W1h = (unsigned short*)alloc(16384 * 2);
    unsigned short* W1l = (unsigned short*)alloc(16384 * 2);
    unsigned short* W3h = (unsigned short*)alloc(16384 * 2);
    unsigned short* W3l = (unsigned short*)alloc(16384 * 2);

    hipLaunchKernelGGL(kpack, dim3(2), dim3(256), 0, stream, W1, W3, W1h, W1l, W3h, W3l);
    hipLaunchKernelGGL(k0_bits, dim3(NB * 8), dim3(256), 0, stream, adj, bits, bitsT, flags);
    hipLaunchKernelGGL(gemm128, dim3(1024), dim3(256), 0, stream, x, W1h, W1l, b1, xh);
    hipLaunchKernelGGL(k1b_softmax, dim3(4096), dim3(256), 0, stream, xh, W2, W4, s, eu);
    hipLaunchKernelGGL(k2_mfma, dim3(NB * HH), dim3(1024), 0, stream, xh, s, bitsT, heg);
    hipLaunchKernelGGL(gemm128_heT, dim3(512), dim3(256), 0, stream, heg, W3h, W3l, b3, he, heT);
    hipLaunchKernelGGL(k3b_ev, dim3(8192), dim3(256), 0, stream, he, W4, ev);
    hipLaunchKernelGGL(k4_dense, dim3(NB * 8), dim3(256), 0, stream, eu, ev, bits, rdm);
    hipLaunchKernelGGL(k5_mfma, dim3(NB * HH), dim3(1024), 0, stream, heT, rdm, eu, ev, flags, x, out);
}